// Round 1
// baseline (443.493 us; speedup 1.0000x reference)
//
#include <hip/hip_runtime.h>
#include <stdint.h>

#define Ddim 256
#define Hdim 1024
#define LSEQ 3072
#define TT 64
#define HC 64

typedef __bf16 bf16x8 __attribute__((ext_vector_type(8)));
typedef unsigned short u16x8 __attribute__((ext_vector_type(8)));
typedef float f32x4 __attribute__((ext_vector_type(4)));

#define MFMA(a, b, c) __builtin_amdgcn_mfma_f32_16x16x32_bf16( \
    __builtin_bit_cast(bf16x8, (a)), __builtin_bit_cast(bf16x8, (b)), (c), 0, 0, 0)

__device__ __forceinline__ unsigned short f2bf(float f) {
  unsigned int u = __float_as_uint(f);
  u = u + 0x7FFFu + ((u >> 16) & 1u);
  return (unsigned short)(u >> 16);
}

__device__ __forceinline__ float gelu_t(float x) {
  // jax.nn.gelu(approximate=True): 0.5*x*(1+tanh(0.7978845608*(x+0.044715*x^3)))
  float t = 0.7978845608028654f * (x + 0.044715f * x * x * x);
  float e = __expf(2.0f * t);
  float th = 1.0f - 2.0f / (e + 1.0f);   // tanh, graceful at +/-inf
  return 0.5f * x * (1.0f + th);
}

// ---------------- gating ----------------

__global__ void zero_seg(float* p) {
  p[blockIdx.x * 256 + threadIdx.x] = 0.0f;
}

// grid (24, 8): per (l-block of 128, batch); thread = d. Accumulate segment sums.
__global__ void seg_reduce(const float* __restrict__ x, float* __restrict__ seg) {
  int lb = blockIdx.x, b = blockIdx.y, tid = threadIdx.x;
  const float* xg = x + ((size_t)b * LSEQ + (size_t)lb * 128) * Ddim + tid;
  float s = 0.0f;
  #pragma unroll 8
  for (int r = 0; r < 128; ++r) s += xg[(size_t)r * Ddim];
  int sg = lb >> 3;  // 8 l-blocks per 1024-token segment
  atomicAdd(&seg[(b * 3 + sg) * Ddim + tid], s);
}

// 1 block, 512 threads: wave w handles batch w.
__global__ void gate_kernel(const float* __restrict__ seg, const float* __restrict__ tc,
                            const float* __restrict__ gw, const float* __restrict__ gb,
                            const float* __restrict__ tw, const float* __restrict__ tb,
                            float* __restrict__ wbe) {
  int b = threadIdx.x >> 6, lane = threadIdx.x & 63;
  const float* sb_ = seg + b * 3 * 256;
  float pl[4] = {0.f, 0.f, 0.f, 0.f};
  for (int i = lane; i < 768; i += 64) {
    int d = i & 255, rg = i >> 8;
    float Sh = sb_[d], Sw = sb_[256 + d], Sp = sb_[512 + d];
    float val = (rg == 0) ? (Sh + Sw + Sp) * (1.0f / 3072.0f)
              : (rg == 1) ? (Sh + Sp) * (1.0f / 2048.0f)
                          : (Sw + Sp) * (1.0f / 2048.0f);
    #pragma unroll
    for (int e = 0; e < 4; ++e) pl[e] += val * gw[i * 4 + e];
  }
  float pm[8] = {0.f, 0.f, 0.f, 0.f, 0.f, 0.f, 0.f, 0.f};
  for (int d = lane; d < 256; d += 64) {
    float t = tc[b * 256 + d];
    float s = t / (1.0f + __expf(-t));  // silu
    #pragma unroll
    for (int j = 0; j < 8; ++j) pm[j] += s * tw[d * 8 + j];
  }
  #pragma unroll
  for (int off = 32; off > 0; off >>= 1) {
    #pragma unroll
    for (int e = 0; e < 4; ++e) pl[e] += __shfl_down(pl[e], off);
    #pragma unroll
    for (int j = 0; j < 8; ++j) pm[j] += __shfl_down(pm[j], off);
  }
  if (lane == 0) {
    #pragma unroll
    for (int j = 0; j < 8; ++j) pm[j] += tb[j];
    float lg[4], sc[4];
    #pragma unroll
    for (int e = 0; e < 4; ++e) lg[e] = (pl[e] + gb[e]) * (1.0f + pm[e]) + pm[4 + e];
    float mx = fmaxf(fmaxf(lg[0], lg[1]), fmaxf(lg[2], lg[3]));
    float s = 0.0f;
    #pragma unroll
    for (int e = 0; e < 4; ++e) { sc[e] = __expf(lg[e] - mx); s += sc[e]; }
    #pragma unroll
    for (int e = 0; e < 4; ++e) sc[e] /= s;
    int i1 = 0;
    #pragma unroll
    for (int e = 1; e < 4; ++e) if (sc[e] > sc[i1]) i1 = e;
    int i2 = (i1 == 0) ? 1 : 0;
    #pragma unroll
    for (int e = 0; e < 4; ++e) if (e != i1 && sc[e] > sc[i2]) i2 = e;
    float den = sc[i1] + sc[i2] + 1e-8f;
    #pragma unroll
    for (int e = 0; e < 4; ++e)
      wbe[b * 4 + e] = (e == i1) ? sc[i1] / den : ((e == i2) ? sc[i2] / den : 0.0f);
  }
}

// ---------------- weight prep: f32 -> bf16 transpose ----------------

// W1-type: src [256][1024] f32 -> dst [1024][256] bf16 (dst[h][d] = src[d][h])
__global__ void transpose_w1(const float* __restrict__ ew1, const float* __restrict__ sw1,
                             unsigned short* __restrict__ dst) {
  int z = blockIdx.z;
  const float* src = (z < 4) ? (ew1 + (size_t)z * Ddim * Hdim) : sw1;
  unsigned short* dz = dst + (size_t)z * Hdim * Ddim;
  __shared__ float tile[32][33];
  int tx = threadIdx.x & 31, ty = threadIdx.x >> 5;
  int c0 = blockIdx.x * 32;  // h
  int r0 = blockIdx.y * 32;  // d
  #pragma unroll
  for (int j = 0; j < 4; ++j)
    tile[ty + 8 * j][tx] = src[(size_t)(r0 + ty + 8 * j) * Hdim + c0 + tx];
  __syncthreads();
  #pragma unroll
  for (int j = 0; j < 4; ++j)
    dz[(size_t)(c0 + ty + 8 * j) * Ddim + r0 + tx] = f2bf(tile[tx][ty + 8 * j]);
}

// W2-type: src [1024][256] f32 -> dst [256][1024] bf16 (dst[d][h] = src[h][d])
__global__ void transpose_w2(const float* __restrict__ ew2, const float* __restrict__ sw2,
                             unsigned short* __restrict__ dst) {
  int z = blockIdx.z;
  const float* src = (z < 4) ? (ew2 + (size_t)z * Hdim * Ddim) : sw2;
  unsigned short* dz = dst + (size_t)z * Ddim * Hdim;
  __shared__ float tile[32][33];
  int tx = threadIdx.x & 31, ty = threadIdx.x >> 5;
  int c0 = blockIdx.x * 32;  // d
  int r0 = blockIdx.y * 32;  // h
  #pragma unroll
  for (int j = 0; j < 4; ++j)
    tile[ty + 8 * j][tx] = src[(size_t)(r0 + ty + 8 * j) * Ddim + c0 + tx];
  __syncthreads();
  #pragma unroll
  for (int j = 0; j < 4; ++j)
    dz[(size_t)(c0 + ty + 8 * j) * Hdim + r0 + tx] = f2bf(tile[tx][ty + 8 * j]);
}

// ---------------- main fused MoE-MLP kernel ----------------
// grid (48, 8): (64-token tile, batch). 256 threads = 4 waves.
// LDS (ushort units, pitches padded so 16-lane b128 read groups are 2-way on banks = free):
//   buf1 @ 0     : x_tile [64][264] (used once) then W2 chunk [256][72]
//   buf2 @ 18432 : W1 chunk [64][264]   (W1T rows h, cols d; pitch 528B)
//   hid  @ 35328 : [64][72]             (pitch 144B)
#define X_OFF 0
#define W2_OFF 0
#define W1_OFF 18432
#define HID_OFF 35328

__global__ __launch_bounds__(256, 2) void moe_main(
    const float* __restrict__ x, const unsigned short* __restrict__ wsW1,
    const unsigned short* __restrict__ wsW2, const float* __restrict__ eb1,
    const float* __restrict__ sb1, const float* __restrict__ eb2,
    const float* __restrict__ sb2, const float* __restrict__ wbe,
    float* __restrict__ out) {
  __shared__ unsigned short smem[39936];

  const int tid = threadIdx.x;
  const int wave = tid >> 6, lane = tid & 63;
  const int lr = lane & 15, lg = lane >> 4;
  const int wm = wave >> 1, wn = wave & 1;  // stage-1 wave grid 2x2
  const int b = blockIdx.y;
  const int l0 = blockIdx.x * TT;
  const int seg = blockIdx.x >> 4;  // 16 tiles per 1024-token segment

  // ---- stage x tile (f32 -> bf16) into buf1 ----
  const float* xg = x + ((size_t)b * LSEQ + l0) * Ddim;
  #pragma unroll
  for (int i = 0; i < 16; ++i) {
    int idx = tid + i * 256;
    int r = idx >> 6, u = idx & 63;
    float4 v = *(const float4*)(xg + (size_t)r * Ddim + u * 4);
    ushort4 pv;
    pv.x = f2bf(v.x); pv.y = f2bf(v.y); pv.z = f2bf(v.z); pv.w = f2bf(v.w);
    *(ushort4*)&smem[X_OFF + r * 264 + u * 4] = pv;
  }
  __syncthreads();

  // ---- load x A-fragments to registers (reused for all chunks/MLPs) ----
  // stage-1: wave covers rows wm*32..wm*32+31 (2 m-frags), A[row][k], k=8*lg+i
  u16x8 xf[8][2];
  #pragma unroll
  for (int k = 0; k < 8; ++k) {
    xf[k][0] = *(const u16x8*)&smem[X_OFF + (wm * 32 + lr) * 264 + k * 32 + lg * 8];
    xf[k][1] = *(const u16x8*)&smem[X_OFF + (wm * 32 + 16 + lr) * 264 + k * 32 + lg * 8];
  }
  __syncthreads();  // buf1 now reusable for W2 chunks

  // ---- active MLP list: shared + selected&unmasked experts ----
  float wv0 = wbe[b * 4 + 0], wv1 = wbe[b * 4 + 1], wv2 = wbe[b * 4 + 2], wv3 = wbe[b * 4 + 3];
  int widx[3]; float wsc[3]; int nm = 0;
  widx[nm] = 4; wsc[nm] = 1.0f; ++nm;                       // shared MLP
  if (wv0 > 0.0f) { widx[nm] = 0; wsc[nm] = wv0; ++nm; }
  if (wv1 > 0.0f && seg != 1) { widx[nm] = 1; wsc[nm] = wv1; ++nm; }  // head|prop
  if (wv2 > 0.0f && seg != 0) { widx[nm] = 2; wsc[nm] = wv2; ++nm; }  // wrist|prop
  if (wv3 > 0.0f && nm < 3) { widx[nm] = 3; wsc[nm] = wv3; ++nm; }

  // persistent output accumulator: wave covers cols wave*64..+63, all 64 rows
  f32x4 oacc[4][4];
  const f32x4 fz = {0.f, 0.f, 0.f, 0.f};
  #pragma unroll
  for (int mf = 0; mf < 4; ++mf)
    #pragma unroll
    for (int nf = 0; nf < 4; ++nf) oacc[mf][nf] = fz;

  for (int m = 0; m < nm; ++m) {
    const int id = widx[m];
    const float wscale = wsc[m];
    const unsigned short* w1g = wsW1 + (size_t)id * Hdim * Ddim;  // [1024][256]
    const unsigned short* w2g = wsW2 + (size_t)id * Ddim * Hdim;  // [256][1024]
    const float* b1g = (id < 4) ? (eb1 + id * Hdim) : sb1;

    for (int hc = 0; hc < 16; ++hc) {
      const int h0 = hc * HC;
      // stage W1 chunk: rows hh (h = h0+hh), cols d. 64x256 bf16 = 32KB
      const unsigned short* w1c = w1g + (size_t)h0 * Ddim;
      #pragma unroll
      for (int i = 0; i < 8; ++i) {
        int idx = tid + i * 256;
        int hh = idx >> 5, u = idx & 31;
        *(u16x8*)&smem[W1_OFF + hh * 264 + u * 8] = *(const u16x8*)&w1c[(size_t)hh * Ddim + u * 8];
      }
      // stage W2 chunk: rows d, cols h_local. 256x64 bf16 = 32KB
      #pragma unroll
      for (int i = 0; i < 8; ++i) {
        int idx = tid + i * 256;
        int dd = idx >> 3, u = idx & 7;
        *(u16x8*)&smem[W2_OFF + dd * 72 + u * 8] = *(const u16x8*)&w2g[(size_t)dd * Hdim + h0 + u * 8];
      }
      __syncthreads();

      // ---- stage 1: hid(64xHC) = gelu(x @ W1c + b1) * wscale ----
      f32x4 a1[2][2];
      a1[0][0] = fz; a1[0][1] = fz; a1[1][0] = fz; a1[1][1] = fz;
      #pragma unroll
      for (int k = 0; k < 8; ++k) {
        u16x8 bf0 = *(const u16x8*)&smem[W1_OFF + (wn * 32 + lr) * 264 + k * 32 + lg * 8];
        u16x8 bf1 = *(const u16x8*)&smem[W1_OFF + (wn * 32 + 16 + lr) * 264 + k * 32 + lg * 8];
        a1[0][0] = MFMA(xf[k][0], bf0, a1[0][0]);
        a1[0][1] = MFMA(xf[k][0], bf1, a1[0][1]);
        a1[1][0] = MFMA(xf[k][1], bf0, a1[1][0]);
        a1[1][1] = MFMA(xf[k][1], bf1, a1[1][1]);
      }
      #pragma unroll
      for (int nf = 0; nf < 2; ++nf) {
        int hl = wn * 32 + nf * 16 + lr;
        float b1v = b1g[h0 + hl];
        #pragma unroll
        for (int mf = 0; mf < 2; ++mf) {
          #pragma unroll
          for (int r = 0; r < 4; ++r) {
            int row = wm * 32 + mf * 16 + lg * 4 + r;   // C/D: row=(lane>>4)*4+r
            float v = a1[mf][nf][r] + b1v;
            v = gelu_t(v) * wscale;
            smem[HID_OFF + row * 72 + hl] = f2bf(v);
          }
        }
      }
      __syncthreads();

      // ---- stage 2: oacc += hid @ W2c ---- (wave: 64 rows x 64 cols)
      #pragma unroll
      for (int k2 = 0; k2 < 2; ++k2) {
        u16x8 ha[4], wb[4];
        #pragma unroll
        for (int mf = 0; mf < 4; ++mf)
          ha[mf] = *(const u16x8*)&smem[HID_OFF + (mf * 16 + lr) * 72 + k2 * 32 + lg * 8];
        #pragma unroll
        for (int nf = 0; nf < 4; ++nf)
          wb[nf] = *(const u16x8*)&smem[W2_OFF + (wave * 64 + nf * 16 + lr) * 72 + k2 * 32 + lg * 8];
        #pragma unroll
        for (int mf = 0; mf < 4; ++mf)
          #pragma unroll
          for (int nf = 0; nf < 4; ++nf)
            oacc[mf][nf] = MFMA(ha[mf], wb[nf], oacc[mf][nf]);
      }
      __syncthreads();
    }
  }

  // ---- epilogue: add b2 terms and store ----
  float* og = out + ((size_t)b * LSEQ + l0) * Ddim;
  #pragma unroll
  for (int nf = 0; nf < 4; ++nf) {
    int dcol = wave * 64 + nf * 16 + lr;
    float bias = sb2[dcol];
    for (int m = 0; m < nm; ++m)
      if (widx[m] < 4) bias += wsc[m] * eb2[widx[m] * Ddim + dcol];
    #pragma unroll
    for (int mf = 0; mf < 4; ++mf)
      #pragma unroll
      for (int r = 0; r < 4; ++r)
        og[(size_t)(mf * 16 + lg * 4 + r) * Ddim + dcol] = oacc[mf][nf][r] + bias;
  }
}

// ---------------- launch ----------------

extern "C" void kernel_launch(void* const* d_in, const int* in_sizes, int n_in,
                              void* d_out, int out_size, void* d_ws, size_t ws_size,
                              hipStream_t stream) {
  const float* x      = (const float*)d_in[0];
  const float* tc     = (const float*)d_in[1];
  const float* gate_w = (const float*)d_in[2];
  const float* gate_b = (const float*)d_in[3];
  const float* tmod_w = (const float*)d_in[4];
  const float* tmod_b = (const float*)d_in[5];
  const float* ew1    = (const float*)d_in[6];
  const float* eb1    = (const float*)d_in[7];
  const float* ew2    = (const float*)d_in[8];
  const float* eb2    = (const float*)d_in[9];
  const float* sw1    = (const float*)d_in[10];
  const float* sb1    = (const float*)d_in[11];
  const float* sw2    = (const float*)d_in[12];
  const float* sb2    = (const float*)d_in[13];
  float* out = (float*)d_out;

  char* wsb = (char*)d_ws;
  float* ws_seg = (float*)wsb;                               // 8*3*256 f32
  float* ws_wbe = (float*)(wsb + 24576);                     // 8*4 f32
  unsigned short* wsW1 = (unsigned short*)(wsb + 32768);     // [5][1024][256] bf16
  unsigned short* wsW2 = wsW1 + (size_t)5 * 1024 * 256;      // [5][256][1024] bf16

  zero_seg<<<24, 256, 0, stream>>>(ws_seg);
  seg_reduce<<<dim3(24, 8), 256, 0, stream>>>(x, ws_seg);
  gate_kernel<<<1, 512, 0, stream>>>(ws_seg, tc, gate_w, gate_b, tmod_w, tmod_b, ws_wbe);
  transpose_w1<<<dim3(32, 8, 5), 256, 0, stream>>>(ew1, sw1, wsW1);
  transpose_w2<<<dim3(8, 32, 5), 256, 0, stream>>>(ew2, sw2, wsW2);
  moe_main<<<dim3(48, 8), 256, 0, stream>>>(x, wsW1, wsW2, eb1, sb1, eb2, sb2, ws_wbe, out);
}

// Round 2
// 439.332 us; speedup vs baseline: 1.0095x; 1.0095x over previous
//
#include <hip/hip_runtime.h>
#include <stdint.h>

#define Ddim 256
#define Hdim 1024
#define LSEQ 3072

typedef __bf16 bf16x8 __attribute__((ext_vector_type(8)));
typedef unsigned short u16x8 __attribute__((ext_vector_type(8)));
typedef float f32x4 __attribute__((ext_vector_type(4)));

#define MFMA(a, b, c) __builtin_amdgcn_mfma_f32_16x16x32_bf16( \
    __builtin_bit_cast(bf16x8, (a)), __builtin_bit_cast(bf16x8, (b)), (c), 0, 0, 0)

__device__ __forceinline__ unsigned short f2bf(float f) {
  unsigned int u = __float_as_uint(f);
  u = u + 0x7FFFu + ((u >> 16) & 1u);
  return (unsigned short)(u >> 16);
}

__device__ __forceinline__ float gelu_t(float x) {
  float t = 0.7978845608028654f * (x + 0.044715f * x * x * x);
  float e = __expf(2.0f * t);
  float th = 1.0f - 2.0f / (e + 1.0f);
  return 0.5f * x * (1.0f + th);
}

// Active-MLP list for (batch b, segment seg): shared MLP + selected unmasked experts.
__device__ __forceinline__ int gate_list(const float* __restrict__ wbe, int b, int seg,
                                         int* widx, float* wsc) {
  float wv0 = wbe[b * 4 + 0], wv1 = wbe[b * 4 + 1];
  float wv2 = wbe[b * 4 + 2], wv3 = wbe[b * 4 + 3];
  int nm = 0;
  widx[nm] = 4; wsc[nm] = 1.0f; ++nm;                       // shared MLP
  if (wv0 > 0.0f) { widx[nm] = 0; wsc[nm] = wv0; ++nm; }
  if (wv1 > 0.0f && seg != 1) { widx[nm] = 1; wsc[nm] = wv1; ++nm; }  // head|prop
  if (wv2 > 0.0f && seg != 0) { widx[nm] = 2; wsc[nm] = wv2; ++nm; }  // wrist|prop
  if (wv3 > 0.0f && nm < 3) { widx[nm] = 3; wsc[nm] = wv3; ++nm; }
  return nm;
}

// ---------------- gating ----------------

__global__ void zero_seg(float* p) {
  p[blockIdx.x * 256 + threadIdx.x] = 0.0f;
}

__global__ void seg_reduce(const float* __restrict__ x, float* __restrict__ seg) {
  int lb = blockIdx.x, b = blockIdx.y, tid = threadIdx.x;
  const float* xg = x + ((size_t)b * LSEQ + (size_t)lb * 128) * Ddim + tid;
  float s = 0.0f;
  #pragma unroll 8
  for (int r = 0; r < 128; ++r) s += xg[(size_t)r * Ddim];
  int sg = lb >> 3;
  atomicAdd(&seg[(b * 3 + sg) * Ddim + tid], s);
}

__global__ void gate_kernel(const float* __restrict__ seg, const float* __restrict__ tc,
                            const float* __restrict__ gw, const float* __restrict__ gb,
                            const float* __restrict__ tw, const float* __restrict__ tb,
                            float* __restrict__ wbe) {
  int b = threadIdx.x >> 6, lane = threadIdx.x & 63;
  const float* sb_ = seg + b * 3 * 256;
  float pl[4] = {0.f, 0.f, 0.f, 0.f};
  for (int i = lane; i < 768; i += 64) {
    int d = i & 255, rg = i >> 8;
    float Sh = sb_[d], Sw = sb_[256 + d], Sp = sb_[512 + d];
    float val = (rg == 0) ? (Sh + Sw + Sp) * (1.0f / 3072.0f)
              : (rg == 1) ? (Sh + Sp) * (1.0f / 2048.0f)
                          : (Sw + Sp) * (1.0f / 2048.0f);
    #pragma unroll
    for (int e = 0; e < 4; ++e) pl[e] += val * gw[i * 4 + e];
  }
  float pm[8] = {0.f, 0.f, 0.f, 0.f, 0.f, 0.f, 0.f, 0.f};
  for (int d = lane; d < 256; d += 64) {
    float t = tc[b * 256 + d];
    float s = t / (1.0f + __expf(-t));
    #pragma unroll
    for (int j = 0; j < 8; ++j) pm[j] += s * tw[d * 8 + j];
  }
  #pragma unroll
  for (int off = 32; off > 0; off >>= 1) {
    #pragma unroll
    for (int e = 0; e < 4; ++e) pl[e] += __shfl_down(pl[e], off);
    #pragma unroll
    for (int j = 0; j < 8; ++j) pm[j] += __shfl_down(pm[j], off);
  }
  if (lane == 0) {
    #pragma unroll
    for (int j = 0; j < 8; ++j) pm[j] += tb[j];
    float lg[4], sc[4];
    #pragma unroll
    for (int e = 0; e < 4; ++e) lg[e] = (pl[e] + gb[e]) * (1.0f + pm[e]) + pm[4 + e];
    float mx = fmaxf(fmaxf(lg[0], lg[1]), fmaxf(lg[2], lg[3]));
    float s = 0.0f;
    #pragma unroll
    for (int e = 0; e < 4; ++e) { sc[e] = __expf(lg[e] - mx); s += sc[e]; }
    #pragma unroll
    for (int e = 0; e < 4; ++e) sc[e] /= s;
    int i1 = 0;
    #pragma unroll
    for (int e = 1; e < 4; ++e) if (sc[e] > sc[i1]) i1 = e;
    int i2 = (i1 == 0) ? 1 : 0;
    #pragma unroll
    for (int e = 0; e < 4; ++e) if (e != i1 && sc[e] > sc[i2]) i2 = e;
    float den = sc[i1] + sc[i2] + 1e-8f;
    #pragma unroll
    for (int e = 0; e < 4; ++e)
      wbe[b * 4 + e] = (e == i1) ? sc[i1] / den : ((e == i2) ? sc[i2] / den : 0.0f);
  }
}

// ---------------- weight prep: f32 -> bf16 MFMA-fragment layout ----------------
// w1f[id][hc 16][k 8][hg 4][lane 64][8]:
//   = W1[d = k*32 + (lane>>4)*8 + j][h = hc*64 + hg*16 + (lane&15)]   (src [D][H])
__global__ void prep_w1f(const float* __restrict__ ew1, const float* __restrict__ sw1,
                         unsigned short* __restrict__ dst) {
  int gid = blockIdx.x * 256 + threadIdx.x;
  int lane = gid & 63;
  int rest = gid >> 6;
  int hg = rest & 3; rest >>= 2;
  int k = rest & 7; rest >>= 3;
  int hc = rest & 15;
  int id = rest >> 4;
  int lr = lane & 15, lg = lane >> 4;
  int h = hc * 64 + hg * 16 + lr;
  int dbase = k * 32 + lg * 8;
  const float* src = (id < 4) ? (ew1 + (size_t)id * Ddim * Hdim) : sw1;
  u16x8 r;
  #pragma unroll
  for (int j = 0; j < 8; ++j) r[j] = f2bf(src[(size_t)(dbase + j) * Hdim + h]);
  *(u16x8*)&dst[(size_t)gid * 8] = r;
}

// w2f[id][hc 16][k2 2][dg 16][lane 64][8]:
//   = W2[h = hc*64 + k2*32 + (lane>>4)*8 + j][d = dg*16 + (lane&15)]  (src [H][D])
__global__ void prep_w2f(const float* __restrict__ ew2, const float* __restrict__ sw2,
                         unsigned short* __restrict__ dst) {
  int gid = blockIdx.x * 256 + threadIdx.x;
  int lane = gid & 63;
  int rest = gid >> 6;
  int dg = rest & 15; rest >>= 4;
  int k2 = rest & 1; rest >>= 1;
  int hc = rest & 15;
  int id = rest >> 4;
  int lr = lane & 15, lg = lane >> 4;
  int d = dg * 16 + lr;
  int hbase = hc * 64 + k2 * 32 + lg * 8;
  const float* src = (id < 4) ? (ew2 + (size_t)id * Hdim * Ddim) : sw2;
  u16x8 r;
  #pragma unroll
  for (int j = 0; j < 8; ++j) r[j] = f2bf(src[(size_t)(hbase + j) * Ddim + d]);
  *(u16x8*)&dst[(size_t)gid * 8] = r;
}

// ---------------- out init: write bias terms ----------------
__global__ void out_init(const float* __restrict__ wbe, const float* __restrict__ eb2,
                         const float* __restrict__ sb2, float* __restrict__ out) {
  int t = blockIdx.x, b = blockIdx.y, tid = threadIdx.x;
  int seg = t >> 4;
  int widx[3]; float wsc[3];
  int nm = gate_list(wbe, b, seg, widx, wsc);
  int d4 = (tid & 63) * 4;
  float4 bias = *(const float4*)&sb2[d4];
  for (int m = 1; m < nm; ++m) {
    if (widx[m] < 4) {
      const float4 e = *(const float4*)&eb2[widx[m] * Ddim + d4];
      bias.x += wsc[m] * e.x; bias.y += wsc[m] * e.y;
      bias.z += wsc[m] * e.z; bias.w += wsc[m] * e.w;
    }
  }
  float* og = out + ((size_t)b * LSEQ + t * 64 + (tid >> 6) * 16) * Ddim + d4;
  #pragma unroll
  for (int r = 0; r < 16; ++r) *(float4*)&og[(size_t)r * Ddim] = bias;
}

// ---------------- main fused MoE-MLP kernel ----------------
// grid (48, 8, 3): (64-token tile, batch, MLP slot). 256 threads = 4 waves.
// Weights come fragment-ready from L2 (no LDS staging). LDS = hid only (9.2KB).
__global__ __launch_bounds__(256, 4) void moe_main(
    const float* __restrict__ x, const unsigned short* __restrict__ w1f,
    const unsigned short* __restrict__ w2f, const float* __restrict__ eb1,
    const float* __restrict__ sb1, const float* __restrict__ wbe,
    float* __restrict__ out) {
  __shared__ unsigned short hid[64 * 72];  // [token][h] pitch 72 (2-way banks on b128)

  const int tid = threadIdx.x;
  const int wave = tid >> 6, lane = tid & 63;
  const int lr = lane & 15, lg = lane >> 4;
  const int wm = wave >> 1, wn = wave & 1;  // stage-1 wave grid 2x2
  const int b = blockIdx.y;
  const int l0 = blockIdx.x * 64;
  const int seg = blockIdx.x >> 4;

  int widx[3]; float wsc[3];
  int nm = gate_list(wbe, b, seg, widx, wsc);
  const int slot = blockIdx.z;
  if (slot >= nm) return;
  const int id = widx[slot];
  const float wscale = wsc[slot];

  // ---- x A-fragments direct global->reg (f32 -> bf16) ----
  u16x8 xf[8][2];
  const float* xb = x + ((size_t)(b * LSEQ + l0 + wm * 32 + lr)) * Ddim;
  #pragma unroll
  for (int k = 0; k < 8; ++k) {
    #pragma unroll
    for (int mf = 0; mf < 2; ++mf) {
      const float* p = xb + (size_t)(mf * 16) * Ddim + k * 32 + lg * 8;
      float4 v0 = *(const float4*)p;
      float4 v1 = *(const float4*)(p + 4);
      u16x8 r;
      r[0] = f2bf(v0.x); r[1] = f2bf(v0.y); r[2] = f2bf(v0.z); r[3] = f2bf(v0.w);
      r[4] = f2bf(v1.x); r[5] = f2bf(v1.y); r[6] = f2bf(v1.z); r[7] = f2bf(v1.w);
      xf[k][mf] = r;
    }
  }

  f32x4 oacc[4][4];
  const f32x4 fz = {0.f, 0.f, 0.f, 0.f};
  #pragma unroll
  for (int mf = 0; mf < 4; ++mf)
    #pragma unroll
    for (int nf = 0; nf < 4; ++nf) oacc[mf][nf] = fz;

  const unsigned short* w1p = w1f + (size_t)id * (16 * 8 * 4 * 512);
  const unsigned short* w2p = w2f + (size_t)id * (16 * 2 * 16 * 512);
  const float* b1g = (id < 4) ? (eb1 + id * Hdim) : sb1;

  for (int hc = 0; hc < 16; ++hc) {
    // ---- stage 1: a1 = x @ W1chunk ----
    f32x4 a1[2][2];
    a1[0][0] = fz; a1[0][1] = fz; a1[1][0] = fz; a1[1][1] = fz;
    const unsigned short* w1c = w1p + (size_t)hc * (8 * 4 * 512) + (wn * 2) * 512 + lane * 8;
    #pragma unroll
    for (int k = 0; k < 8; ++k) {
      u16x8 b0 = *(const u16x8*)(w1c + (size_t)k * (4 * 512));
      u16x8 b1 = *(const u16x8*)(w1c + (size_t)k * (4 * 512) + 512);
      a1[0][0] = MFMA(xf[k][0], b0, a1[0][0]);
      a1[0][1] = MFMA(xf[k][0], b1, a1[0][1]);
      a1[1][0] = MFMA(xf[k][1], b0, a1[1][0]);
      a1[1][1] = MFMA(xf[k][1], b1, a1[1][1]);
    }
    // bias + gelu + gate-weight -> hid
    #pragma unroll
    for (int nf = 0; nf < 2; ++nf) {
      int hl = wn * 32 + nf * 16 + lr;
      float b1v = b1g[hc * 64 + hl];
      #pragma unroll
      for (int mf = 0; mf < 2; ++mf) {
        #pragma unroll
        for (int r = 0; r < 4; ++r) {
          int row = wm * 32 + mf * 16 + lg * 4 + r;
          hid[row * 72 + hl] = f2bf(gelu_t(a1[mf][nf][r] + b1v) * wscale);
        }
      }
    }
    __syncthreads();

    // ---- stage 2: oacc += hid @ W2chunk ----
    const unsigned short* w2c = w2p + (size_t)hc * (2 * 16 * 512) + (wave * 4) * 512 + lane * 8;
    #pragma unroll
    for (int k2 = 0; k2 < 2; ++k2) {
      u16x8 ha[4], wb[4];
      #pragma unroll
      for (int mf = 0; mf < 4; ++mf)
        ha[mf] = *(const u16x8*)&hid[(mf * 16 + lr) * 72 + k2 * 32 + lg * 8];
      #pragma unroll
      for (int nf = 0; nf < 4; ++nf)
        wb[nf] = *(const u16x8*)(w2c + (size_t)k2 * (16 * 512) + nf * 512);
      #pragma unroll
      for (int mf = 0; mf < 4; ++mf)
        #pragma unroll
        for (int nf = 0; nf < 4; ++nf)
          oacc[mf][nf] = MFMA(ha[mf], wb[nf], oacc[mf][nf]);
    }
    __syncthreads();
  }

  // ---- epilogue: atomic accumulate into out (bias already written by out_init) ----
  float* og = out + ((size_t)b * LSEQ + l0) * Ddim;
  #pragma unroll
  for (int nf = 0; nf < 4; ++nf) {
    int dcol = wave * 64 + nf * 16 + lr;
    #pragma unroll
    for (int mf = 0; mf < 4; ++mf)
      #pragma unroll
      for (int r = 0; r < 4; ++r)
        atomicAdd(&og[(size_t)(mf * 16 + lg * 4 + r) * Ddim + dcol], oacc[mf][nf][r]);
  }
}

// ---------------- launch ----------------

extern "C" void kernel_launch(void* const* d_in, const int* in_sizes, int n_in,
                              void* d_out, int out_size, void* d_ws, size_t ws_size,
                              hipStream_t stream) {
  const float* x      = (const float*)d_in[0];
  const float* tc     = (const float*)d_in[1];
  const float* gate_w = (const float*)d_in[2];
  const float* gate_b = (const float*)d_in[3];
  const float* tmod_w = (const float*)d_in[4];
  const float* tmod_b = (const float*)d_in[5];
  const float* ew1    = (const float*)d_in[6];
  const float* eb1    = (const float*)d_in[7];
  const float* ew2    = (const float*)d_in[8];
  const float* eb2    = (const float*)d_in[9];
  const float* sw1    = (const float*)d_in[10];
  const float* sb1    = (const float*)d_in[11];
  const float* sw2    = (const float*)d_in[12];
  const float* sb2    = (const float*)d_in[13];
  float* out = (float*)d_out;

  char* wsb = (char*)d_ws;
  float* ws_seg = (float*)wsb;                               // 8*3*256 f32
  float* ws_wbe = (float*)(wsb + 24576);                     // 8*4 f32
  unsigned short* w1f = (unsigned short*)(wsb + 32768);      // 5*16*8*4*512 bf16
  unsigned short* w2f = w1f + (size_t)5 * 16 * 8 * 4 * 512;  // 5*16*2*16*512 bf16

  zero_seg<<<24, 256, 0, stream>>>(ws_seg);
  seg_reduce<<<dim3(24, 8), 256, 0, stream>>>(x, ws_seg);
  gate_kernel<<<1, 512, 0, stream>>>(ws_seg, tc, gate_w, gate_b, tmod_w, tmod_b, ws_wbe);
  prep_w1f<<<640, 256, 0, stream>>>(ew1, sw1, w1f);
  prep_w2f<<<640, 256, 0, stream>>>(ew2, sw2, w2f);
  out_init<<<dim3(48, 8), 256, 0, stream>>>(ws_wbe, eb2, sb2, out);
  moe_main<<<dim3(48, 8, 3), 256, 0, stream>>>(x, w1f, w2f, eb1, sb1, ws_wbe, out);
}

// Round 3
// 436.877 us; speedup vs baseline: 1.0151x; 1.0056x over previous
//
#include <hip/hip_runtime.h>
#include <stdint.h>

#define Ddim 256
#define Hdim 1024
#define LSEQ 3072

typedef __bf16 bf16x8 __attribute__((ext_vector_type(8)));
typedef unsigned short u16x8 __attribute__((ext_vector_type(8)));
typedef float f32x4 __attribute__((ext_vector_type(4)));

#define MFMA(a, b, c) __builtin_amdgcn_mfma_f32_16x16x32_bf16( \
    __builtin_bit_cast(bf16x8, (a)), __builtin_bit_cast(bf16x8, (b)), (c), 0, 0, 0)

__device__ __forceinline__ unsigned short f2bf(float f) {
  unsigned int u = __float_as_uint(f);
  u = u + 0x7FFFu + ((u >> 16) & 1u);
  return (unsigned short)(u >> 16);
}

__device__ __forceinline__ float gelu_t(float x) {
  float t = 0.7978845608028654f * (x + 0.044715f * x * x * x);
  float e = __expf(2.0f * t);
  float th = 1.0f - 2.0f / (e + 1.0f);
  return 0.5f * x * (1.0f + th);
}

// Active-MLP list for (batch b, segment seg): shared MLP + selected unmasked experts.
__device__ __forceinline__ int gate_list(const float* __restrict__ wbe, int b, int seg,
                                         int* widx, float* wsc) {
  float wv0 = wbe[b * 4 + 0], wv1 = wbe[b * 4 + 1];
  float wv2 = wbe[b * 4 + 2], wv3 = wbe[b * 4 + 3];
  int nm = 0;
  widx[nm] = 4; wsc[nm] = 1.0f; ++nm;                       // shared MLP
  if (wv0 > 0.0f) { widx[nm] = 0; wsc[nm] = wv0; ++nm; }
  if (wv1 > 0.0f && seg != 1) { widx[nm] = 1; wsc[nm] = wv1; ++nm; }  // head|prop
  if (wv2 > 0.0f && seg != 0) { widx[nm] = 2; wsc[nm] = wv2; ++nm; }  // wrist|prop
  if (wv3 > 0.0f && nm < 3) { widx[nm] = 3; wsc[nm] = wv3; ++nm; }
  return nm;
}

// ---------------- gating ----------------

__global__ void zero_seg(float* p) {
  p[blockIdx.x * 256 + threadIdx.x] = 0.0f;
}

__global__ void seg_reduce(const float* __restrict__ x, float* __restrict__ seg) {
  int lb = blockIdx.x, b = blockIdx.y, tid = threadIdx.x;
  const float* xg = x + ((size_t)b * LSEQ + (size_t)lb * 128) * Ddim + tid;
  float s = 0.0f;
  #pragma unroll 8
  for (int r = 0; r < 128; ++r) s += xg[(size_t)r * Ddim];
  int sg = lb >> 3;
  atomicAdd(&seg[(b * 3 + sg) * Ddim + tid], s);
}

__global__ void gate_kernel(const float* __restrict__ seg, const float* __restrict__ tc,
                            const float* __restrict__ gw, const float* __restrict__ gb,
                            const float* __restrict__ tw, const float* __restrict__ tb,
                            float* __restrict__ wbe) {
  int b = threadIdx.x >> 6, lane = threadIdx.x & 63;
  const float* sb_ = seg + b * 3 * 256;
  float pl[4] = {0.f, 0.f, 0.f, 0.f};
  for (int i = lane; i < 768; i += 64) {
    int d = i & 255, rg = i >> 8;
    float Sh = sb_[d], Sw = sb_[256 + d], Sp = sb_[512 + d];
    float val = (rg == 0) ? (Sh + Sw + Sp) * (1.0f / 3072.0f)
              : (rg == 1) ? (Sh + Sp) * (1.0f / 2048.0f)
                          : (Sw + Sp) * (1.0f / 2048.0f);
    #pragma unroll
    for (int e = 0; e < 4; ++e) pl[e] += val * gw[i * 4 + e];
  }
  float pm[8] = {0.f, 0.f, 0.f, 0.f, 0.f, 0.f, 0.f, 0.f};
  for (int d = lane; d < 256; d += 64) {
    float t = tc[b * 256 + d];
    float s = t / (1.0f + __expf(-t));
    #pragma unroll
    for (int j = 0; j < 8; ++j) pm[j] += s * tw[d * 8 + j];
  }
  #pragma unroll
  for (int off = 32; off > 0; off >>= 1) {
    #pragma unroll
    for (int e = 0; e < 4; ++e) pl[e] += __shfl_down(pl[e], off);
    #pragma unroll
    for (int j = 0; j < 8; ++j) pm[j] += __shfl_down(pm[j], off);
  }
  if (lane == 0) {
    #pragma unroll
    for (int j = 0; j < 8; ++j) pm[j] += tb[j];
    float lg[4], sc[4];
    #pragma unroll
    for (int e = 0; e < 4; ++e) lg[e] = (pl[e] + gb[e]) * (1.0f + pm[e]) + pm[4 + e];
    float mx = fmaxf(fmaxf(lg[0], lg[1]), fmaxf(lg[2], lg[3]));
    float s = 0.0f;
    #pragma unroll
    for (int e = 0; e < 4; ++e) { sc[e] = __expf(lg[e] - mx); s += sc[e]; }
    #pragma unroll
    for (int e = 0; e < 4; ++e) sc[e] /= s;
    int i1 = 0;
    #pragma unroll
    for (int e = 1; e < 4; ++e) if (sc[e] > sc[i1]) i1 = e;
    int i2 = (i1 == 0) ? 1 : 0;
    #pragma unroll
    for (int e = 0; e < 4; ++e) if (e != i1 && sc[e] > sc[i2]) i2 = e;
    float den = sc[i1] + sc[i2] + 1e-8f;
    #pragma unroll
    for (int e = 0; e < 4; ++e)
      wbe[b * 4 + e] = (e == i1) ? sc[i1] / den : ((e == i2) ? sc[i2] / den : 0.0f);
  }
}

// ---------------- weight prep: f32 -> bf16 MFMA-fragment layout ----------------
// w1f[id][hc 16][k 8][hg 4][lane 64][8]:
//   = W1[d = k*32 + (lane>>4)*8 + j][h = hc*64 + hg*16 + (lane&15)]   (src [D][H])
__global__ void prep_w1f(const float* __restrict__ ew1, const float* __restrict__ sw1,
                         unsigned short* __restrict__ dst) {
  int gid = blockIdx.x * 256 + threadIdx.x;
  int lane = gid & 63;
  int rest = gid >> 6;
  int hg = rest & 3; rest >>= 2;
  int k = rest & 7; rest >>= 3;
  int hc = rest & 15;
  int id = rest >> 4;
  int lr = lane & 15, lg = lane >> 4;
  int h = hc * 64 + hg * 16 + lr;
  int dbase = k * 32 + lg * 8;
  const float* src = (id < 4) ? (ew1 + (size_t)id * Ddim * Hdim) : sw1;
  u16x8 r;
  #pragma unroll
  for (int j = 0; j < 8; ++j) r[j] = f2bf(src[(size_t)(dbase + j) * Hdim + h]);
  *(u16x8*)&dst[(size_t)gid * 8] = r;
}

// w2f[id][hc 16][k2 2][dg 16][lane 64][8]:
//   = W2[h = hc*64 + k2*32 + (lane>>4)*8 + j][d = dg*16 + (lane&15)]  (src [H][D])
__global__ void prep_w2f(const float* __restrict__ ew2, const float* __restrict__ sw2,
                         unsigned short* __restrict__ dst) {
  int gid = blockIdx.x * 256 + threadIdx.x;
  int lane = gid & 63;
  int rest = gid >> 6;
  int dg = rest & 15; rest >>= 4;
  int k2 = rest & 1; rest >>= 1;
  int hc = rest & 15;
  int id = rest >> 4;
  int lr = lane & 15, lg = lane >> 4;
  int d = dg * 16 + lr;
  int hbase = hc * 64 + k2 * 32 + lg * 8;
  const float* src = (id < 4) ? (ew2 + (size_t)id * Hdim * Ddim) : sw2;
  u16x8 r;
  #pragma unroll
  for (int j = 0; j < 8; ++j) r[j] = f2bf(src[(size_t)(hbase + j) * Ddim + d]);
  *(u16x8*)&dst[(size_t)gid * 8] = r;
}

// ---------------- out init: write bias terms ----------------
__global__ void out_init(const float* __restrict__ wbe, const float* __restrict__ eb2,
                         const float* __restrict__ sb2, float* __restrict__ out) {
  int t = blockIdx.x, b = blockIdx.y, tid = threadIdx.x;
  int seg = t >> 4;
  int widx[3]; float wsc[3];
  int nm = gate_list(wbe, b, seg, widx, wsc);
  int d4 = (tid & 63) * 4;
  float4 bias = *(const float4*)&sb2[d4];
  for (int m = 1; m < nm; ++m) {
    if (widx[m] < 4) {
      const float4 e = *(const float4*)&eb2[widx[m] * Ddim + d4];
      bias.x += wsc[m] * e.x; bias.y += wsc[m] * e.y;
      bias.z += wsc[m] * e.z; bias.w += wsc[m] * e.w;
    }
  }
  float* og = out + ((size_t)b * LSEQ + t * 64 + (tid >> 6) * 16) * Ddim + d4;
  #pragma unroll
  for (int r = 0; r < 16; ++r) *(float4*)&og[(size_t)r * Ddim] = bias;
}

// ---------------- main fused MoE-MLP kernel ----------------
// 1-D grid of 1152 blocks, XCD-aware decode: b = i&7 pins all of batch b's
// blocks onto XCD b (round-robin dispatch) -> per-XCD L2 working set = that
// batch's <=3 MLP weight streams (~3MB) < 4MB L2. 256 threads = 4 waves.
__global__ __launch_bounds__(256, 4) void moe_main(
    const float* __restrict__ x, const unsigned short* __restrict__ w1f,
    const unsigned short* __restrict__ w2f, const float* __restrict__ eb1,
    const float* __restrict__ sb1, const float* __restrict__ wbe,
    float* __restrict__ out) {
  __shared__ unsigned short hid[64 * 72];  // [token][h] pitch 72

  const int i = blockIdx.x;
  const int b = i & 7;           // -> XCD id under round-robin dispatch
  const int r_ = i >> 3;         // 0..143
  const int slot = r_ % 3;
  const int t = r_ / 3;          // 0..47

  const int tid = threadIdx.x;
  const int wave = tid >> 6, lane = tid & 63;
  const int lr = lane & 15, lg = lane >> 4;
  const int wm = wave >> 1, wn = wave & 1;  // stage-1 wave grid 2x2
  const int l0 = t * 64;
  const int seg = t >> 4;

  int widx[3]; float wsc[3];
  int nm = gate_list(wbe, b, seg, widx, wsc);
  if (slot >= nm) return;
  const int id = widx[slot];
  const float wscale = wsc[slot];

  // ---- x A-fragments direct global->reg (f32 -> bf16) ----
  u16x8 xf[8][2];
  const float* xb = x + ((size_t)(b * LSEQ + l0 + wm * 32 + lr)) * Ddim;
  #pragma unroll
  for (int k = 0; k < 8; ++k) {
    #pragma unroll
    for (int mf = 0; mf < 2; ++mf) {
      const float* p = xb + (size_t)(mf * 16) * Ddim + k * 32 + lg * 8;
      float4 v0 = *(const float4*)p;
      float4 v1 = *(const float4*)(p + 4);
      u16x8 r;
      r[0] = f2bf(v0.x); r[1] = f2bf(v0.y); r[2] = f2bf(v0.z); r[3] = f2bf(v0.w);
      r[4] = f2bf(v1.x); r[5] = f2bf(v1.y); r[6] = f2bf(v1.z); r[7] = f2bf(v1.w);
      xf[k][mf] = r;
    }
  }

  f32x4 oacc[4][4];
  const f32x4 fz = {0.f, 0.f, 0.f, 0.f};
  #pragma unroll
  for (int mf = 0; mf < 4; ++mf)
    #pragma unroll
    for (int nf = 0; nf < 4; ++nf) oacc[mf][nf] = fz;

  const unsigned short* w1p = w1f + (size_t)id * (16 * 8 * 4 * 512);
  const unsigned short* w2p = w2f + (size_t)id * (16 * 2 * 16 * 512);
  const float* b1g = (id < 4) ? (eb1 + id * Hdim) : sb1;

  for (int hc = 0; hc < 16; ++hc) {
    // ---- stage 1: a1 = x @ W1chunk ----
    f32x4 a1[2][2];
    a1[0][0] = fz; a1[0][1] = fz; a1[1][0] = fz; a1[1][1] = fz;
    const unsigned short* w1c = w1p + (size_t)hc * (8 * 4 * 512) + (wn * 2) * 512 + lane * 8;
    #pragma unroll
    for (int k = 0; k < 8; ++k) {
      u16x8 b0 = *(const u16x8*)(w1c + (size_t)k * (4 * 512));
      u16x8 b1 = *(const u16x8*)(w1c + (size_t)k * (4 * 512) + 512);
      a1[0][0] = MFMA(xf[k][0], b0, a1[0][0]);
      a1[0][1] = MFMA(xf[k][0], b1, a1[0][1]);
      a1[1][0] = MFMA(xf[k][1], b0, a1[1][0]);
      a1[1][1] = MFMA(xf[k][1], b1, a1[1][1]);
    }
    // bias + gelu + gate-weight -> hid
    #pragma unroll
    for (int nf = 0; nf < 2; ++nf) {
      int hl = wn * 32 + nf * 16 + lr;
      float b1v = b1g[hc * 64 + hl];
      #pragma unroll
      for (int mf = 0; mf < 2; ++mf) {
        #pragma unroll
        for (int r = 0; r < 4; ++r) {
          int row = wm * 32 + mf * 16 + lg * 4 + r;
          hid[row * 72 + hl] = f2bf(gelu_t(a1[mf][nf][r] + b1v) * wscale);
        }
      }
    }
    __syncthreads();

    // ---- stage 2: oacc += hid @ W2chunk ----
    const unsigned short* w2c = w2p + (size_t)hc * (2 * 16 * 512) + (wave * 4) * 512 + lane * 8;
    #pragma unroll
    for (int k2 = 0; k2 < 2; ++k2) {
      u16x8 ha[4], wb[4];
      #pragma unroll
      for (int mf = 0; mf < 4; ++mf)
        ha[mf] = *(const u16x8*)&hid[(mf * 16 + lr) * 72 + k2 * 32 + lg * 8];
      #pragma unroll
      for (int nf = 0; nf < 4; ++nf)
        wb[nf] = *(const u16x8*)(w2c + (size_t)k2 * (16 * 512) + nf * 512);
      #pragma unroll
      for (int mf = 0; mf < 4; ++mf)
        #pragma unroll
        for (int nf = 0; nf < 4; ++nf)
          oacc[mf][nf] = MFMA(ha[mf], wb[nf], oacc[mf][nf]);
    }
    __syncthreads();
  }

  // ---- epilogue: atomic accumulate into out (bias already written by out_init) ----
  float* og = out + ((size_t)b * LSEQ + l0) * Ddim;
  #pragma unroll
  for (int nf = 0; nf < 4; ++nf) {
    int dcol = wave * 64 + nf * 16 + lr;
    #pragma unroll
    for (int mf = 0; mf < 4; ++mf)
      #pragma unroll
      for (int r = 0; r < 4; ++r)
        atomicAdd(&og[(size_t)(mf * 16 + lg * 4 + r) * Ddim + dcol], oacc[mf][nf][r]);
  }
}

// ---------------- launch ----------------

extern "C" void kernel_launch(void* const* d_in, const int* in_sizes, int n_in,
                              void* d_out, int out_size, void* d_ws, size_t ws_size,
                              hipStream_t stream) {
  const float* x      = (const float*)d_in[0];
  const float* tc     = (const float*)d_in[1];
  const float* gate_w = (const float*)d_in[2];
  const float* gate_b = (const float*)d_in[3];
  const float* tmod_w = (const float*)d_in[4];
  const float* tmod_b = (const float*)d_in[5];
  const float* ew1    = (const float*)d_in[6];
  const float* eb1    = (const float*)d_in[7];
  const float* ew2    = (const float*)d_in[8];
  const float* eb2    = (const float*)d_in[9];
  const float* sw1    = (const float*)d_in[10];
  const float* sb1    = (const float*)d_in[11];
  const float* sw2    = (const float*)d_in[12];
  const float* sb2    = (const float*)d_in[13];
  float* out = (float*)d_out;

  char* wsb = (char*)d_ws;
  float* ws_seg = (float*)wsb;                               // 8*3*256 f32
  float* ws_wbe = (float*)(wsb + 24576);                     // 8*4 f32
  unsigned short* w1f = (unsigned short*)(wsb + 32768);      // 5*16*8*4*512 bf16
  unsigned short* w2f = w1f + (size_t)5 * 16 * 8 * 4 * 512;  // 5*16*2*16*512 bf16

  zero_seg<<<24, 256, 0, stream>>>(ws_seg);
  seg_reduce<<<dim3(24, 8), 256, 0, stream>>>(x, ws_seg);
  gate_kernel<<<1, 512, 0, stream>>>(ws_seg, tc, gate_w, gate_b, tmod_w, tmod_b, ws_wbe);
  prep_w1f<<<640, 256, 0, stream>>>(ew1, sw1, w1f);
  prep_w2f<<<640, 256, 0, stream>>>(ew2, sw2, w2f);
  out_init<<<dim3(48, 8), 256, 0, stream>>>(ws_wbe, eb2, sb2, out);
  moe_main<<<1152, 256, 0, stream>>>(x, w1f, w2f, eb1, sb1, ws_wbe, out);
}

// Round 4
// 313.177 us; speedup vs baseline: 1.4161x; 1.3950x over previous
//
#include <hip/hip_runtime.h>
#include <stdint.h>

#define Ddim 256
#define Hdim 1024
#define LSEQ 3072

typedef __bf16 bf16x8 __attribute__((ext_vector_type(8)));
typedef unsigned short u16x8 __attribute__((ext_vector_type(8)));
typedef float f32x4 __attribute__((ext_vector_type(4)));

#define MFMA(a, b, c) __builtin_amdgcn_mfma_f32_16x16x32_bf16( \
    __builtin_bit_cast(bf16x8, (a)), __builtin_bit_cast(bf16x8, (b)), (c), 0, 0, 0)

__device__ __forceinline__ unsigned short f2bf(float f) {
  unsigned int u = __float_as_uint(f);
  u = u + 0x7FFFu + ((u >> 16) & 1u);
  return (unsigned short)(u >> 16);
}

__device__ __forceinline__ float gelu_t(float x) {
  float t = 0.7978845608028654f * (x + 0.044715f * x * x * x);
  float e = __expf(2.0f * t);
  float th = 1.0f - 2.0f / (e + 1.0f);
  return 0.5f * x * (1.0f + th);
}

// Active-MLP list for (batch b, segment seg): shared MLP + selected unmasked experts.
__device__ __forceinline__ int gate_list(const float* __restrict__ wbe, int b, int seg,
                                         int* widx, float* wsc) {
  float wv0 = wbe[b * 4 + 0], wv1 = wbe[b * 4 + 1];
  float wv2 = wbe[b * 4 + 2], wv3 = wbe[b * 4 + 3];
  int nm = 0;
  widx[nm] = 4; wsc[nm] = 1.0f; ++nm;                       // shared MLP
  if (wv0 > 0.0f) { widx[nm] = 0; wsc[nm] = wv0; ++nm; }
  if (wv1 > 0.0f && seg != 1) { widx[nm] = 1; wsc[nm] = wv1; ++nm; }  // head|prop
  if (wv2 > 0.0f && seg != 0) { widx[nm] = 2; wsc[nm] = wv2; ++nm; }  // wrist|prop
  if (wv3 > 0.0f && nm < 3) { widx[nm] = 3; wsc[nm] = wv3; ++nm; }
  return nm;
}

// async global->LDS, 16B/lane, 4KB per call at 256 threads
__device__ __forceinline__ void glds16(const unsigned short* g, unsigned short* l) {
  __builtin_amdgcn_global_load_lds(
      (const __attribute__((address_space(1))) unsigned int*)g,
      (__attribute__((address_space(3))) unsigned int*)l, 16, 0, 0);
}

// ---------------- gating ----------------

__global__ void zero_seg(float* p) {
  p[blockIdx.x * 256 + threadIdx.x] = 0.0f;
}

__global__ void seg_reduce(const float* __restrict__ x, float* __restrict__ seg) {
  int lb = blockIdx.x, b = blockIdx.y, tid = threadIdx.x;
  const float* xg = x + ((size_t)b * LSEQ + (size_t)lb * 128) * Ddim + tid;
  float s = 0.0f;
  #pragma unroll 8
  for (int r = 0; r < 128; ++r) s += xg[(size_t)r * Ddim];
  int sg = lb >> 3;
  atomicAdd(&seg[(b * 3 + sg) * Ddim + tid], s);
}

__global__ void gate_kernel(const float* __restrict__ seg, const float* __restrict__ tc,
                            const float* __restrict__ gw, const float* __restrict__ gb,
                            const float* __restrict__ tw, const float* __restrict__ tb,
                            float* __restrict__ wbe) {
  int b = threadIdx.x >> 6, lane = threadIdx.x & 63;
  const float* sb_ = seg + b * 3 * 256;
  float pl[4] = {0.f, 0.f, 0.f, 0.f};
  for (int i = lane; i < 768; i += 64) {
    int d = i & 255, rg = i >> 8;
    float Sh = sb_[d], Sw = sb_[256 + d], Sp = sb_[512 + d];
    float val = (rg == 0) ? (Sh + Sw + Sp) * (1.0f / 3072.0f)
              : (rg == 1) ? (Sh + Sp) * (1.0f / 2048.0f)
                          : (Sw + Sp) * (1.0f / 2048.0f);
    #pragma unroll
    for (int e = 0; e < 4; ++e) pl[e] += val * gw[i * 4 + e];
  }
  float pm[8] = {0.f, 0.f, 0.f, 0.f, 0.f, 0.f, 0.f, 0.f};
  for (int d = lane; d < 256; d += 64) {
    float t = tc[b * 256 + d];
    float s = t / (1.0f + __expf(-t));
    #pragma unroll
    for (int j = 0; j < 8; ++j) pm[j] += s * tw[d * 8 + j];
  }
  #pragma unroll
  for (int off = 32; off > 0; off >>= 1) {
    #pragma unroll
    for (int e = 0; e < 4; ++e) pl[e] += __shfl_down(pl[e], off);
    #pragma unroll
    for (int j = 0; j < 8; ++j) pm[j] += __shfl_down(pm[j], off);
  }
  if (lane == 0) {
    #pragma unroll
    for (int j = 0; j < 8; ++j) pm[j] += tb[j];
    float lg[4], sc[4];
    #pragma unroll
    for (int e = 0; e < 4; ++e) lg[e] = (pl[e] + gb[e]) * (1.0f + pm[e]) + pm[4 + e];
    float mx = fmaxf(fmaxf(lg[0], lg[1]), fmaxf(lg[2], lg[3]));
    float s = 0.0f;
    #pragma unroll
    for (int e = 0; e < 4; ++e) { sc[e] = __expf(lg[e] - mx); s += sc[e]; }
    #pragma unroll
    for (int e = 0; e < 4; ++e) sc[e] /= s;
    int i1 = 0;
    #pragma unroll
    for (int e = 1; e < 4; ++e) if (sc[e] > sc[i1]) i1 = e;
    int i2 = (i1 == 0) ? 1 : 0;
    #pragma unroll
    for (int e = 0; e < 4; ++e) if (e != i1 && sc[e] > sc[i2]) i2 = e;
    float den = sc[i1] + sc[i2] + 1e-8f;
    #pragma unroll
    for (int e = 0; e < 4; ++e)
      wbe[b * 4 + e] = (e == i1) ? sc[i1] / den : ((e == i2) ? sc[i2] / den : 0.0f);
  }
}

// ---------------- weight prep: coalesced f32 -> bf16 fragment chunks ----------------
// wch[id][hc 32][32KB chunk]: first 8192 u16 = W1 frags [k 8][hg 2][lane 64][8],
//                             last  8192 u16 = W2 frags [dg 16][lane 64][8].
// W1 frag elem j = W1[d = k*32 + lg*8 + j][h = hc*32 + hg*16 + lr]
// W2 frag elem j = W2[h = hc*32 + lg*8 + j][d = dg*16 + lr]

__global__ void prep_w1f_v2(const float* __restrict__ ew1, const float* __restrict__ sw1,
                            unsigned short* __restrict__ wch) {
  int hc = blockIdx.x, id = blockIdx.y;
  const float* src = (id < 4) ? (ew1 + (size_t)id * Ddim * Hdim) : sw1;  // [256][1024]
  __shared__ float tile[256 * 33];   // [d][h'] pitch 33
  int tid = threadIdx.x;
  int h0 = hc * 32;
  #pragma unroll
  for (int p = 0; p < 8; ++p) {
    int row = p * 32 + (tid >> 3);
    int c = (tid & 7) * 4;
    float4 v = *(const float4*)&src[(size_t)row * Hdim + h0 + c];
    tile[row * 33 + c] = v.x; tile[row * 33 + c + 1] = v.y;
    tile[row * 33 + c + 2] = v.z; tile[row * 33 + c + 3] = v.w;
  }
  __syncthreads();
  unsigned short* dst = wch + ((size_t)(id * 32 + hc)) * 16384;
  int lane = tid & 63, lr = lane & 15, lg = lane >> 4;
  #pragma unroll
  for (int p = 0; p < 4; ++p) {
    int f = tid + p * 256;
    int hg = (f >> 6) & 1, k = f >> 7;
    u16x8 r;
    #pragma unroll
    for (int j = 0; j < 8; ++j) r[j] = f2bf(tile[(k * 32 + lg * 8 + j) * 33 + hg * 16 + lr]);
    *(u16x8*)&dst[(size_t)f * 8] = r;
  }
}

__global__ void prep_w2f_v2(const float* __restrict__ ew2, const float* __restrict__ sw2,
                            unsigned short* __restrict__ wch) {
  int hc = blockIdx.x, id = blockIdx.y;
  const float* src = (id < 4) ? (ew2 + (size_t)id * Hdim * Ddim) : sw2;  // [1024][256]
  __shared__ float tile[32 * 264];   // [hh][c + c/32] padded
  int tid = threadIdx.x;
  int h0 = hc * 32;
  #pragma unroll
  for (int p = 0; p < 8; ++p) {
    int hh = p * 4 + (tid >> 6);
    int c = (tid & 63) * 4;
    float4 v = *(const float4*)&src[(size_t)(h0 + hh) * Ddim + c];
    int ci = c + (c >> 5);
    tile[hh * 264 + ci] = v.x; tile[hh * 264 + ci + 1] = v.y;
    tile[hh * 264 + ci + 2] = v.z; tile[hh * 264 + ci + 3] = v.w;
  }
  __syncthreads();
  unsigned short* dst = wch + ((size_t)(id * 32 + hc)) * 16384 + 8192;
  int lane = tid & 63, lr = lane & 15, lg = lane >> 4;
  #pragma unroll
  for (int p = 0; p < 4; ++p) {
    int f = tid + p * 256;
    int dg = f >> 6;
    u16x8 r;
    #pragma unroll
    for (int j = 0; j < 8; ++j) {
      int c = dg * 16 + lr;
      r[j] = f2bf(tile[(lg * 8 + j) * 264 + c + (c >> 5)]);
    }
    *(u16x8*)&dst[(size_t)f * 8] = r;
  }
}

// ---------------- main fused MoE-MLP kernel ----------------
// Grid 384 = (b 8) x (t 48), decode b = i&7 (XCD affinity; uniform duration per b).
// 256 threads = 4 waves. Per iteration (nm*32 total): one 32-KB fragment-ready
// weight chunk staged async into LDS (double-buffered, issued 1 iter ahead),
// stage1 (64x32 = x @ W1c, gelu, -> hid LDS), stage2 (oacc += hid @ W2c).
__global__ __launch_bounds__(256, 2) void moe_main(
    const float* __restrict__ x, const unsigned short* __restrict__ wch,
    const float* __restrict__ eb1, const float* __restrict__ sb1,
    const float* __restrict__ eb2, const float* __restrict__ sb2,
    const float* __restrict__ wbe, float* __restrict__ out) {
  __shared__ __align__(16) unsigned short lds[2 * 16384 + 64 * 40];
  unsigned short* hid = lds + 32768;  // [64][40] u16

  const int i = blockIdx.x;
  const int b = i & 7, t = i >> 3;
  const int tid = threadIdx.x;
  const int wave = tid >> 6, lane = tid & 63;
  const int lr = lane & 15, lg = lane >> 4;
  const int wm = wave >> 1, wn = wave & 1;
  const int seg = t >> 4;

  int widx[3]; float wsc[3];
  const int nm = gate_list(wbe, b, seg, widx, wsc);
  const int total = nm * 32;

  // ---- x A-fragments global->reg (f32 -> bf16), reused across all iterations ----
  u16x8 xf[8][2];
  const float* xb = x + ((size_t)(b * LSEQ + t * 64 + wm * 32 + lr)) * Ddim;
  #pragma unroll
  for (int k = 0; k < 8; ++k) {
    #pragma unroll
    for (int mf = 0; mf < 2; ++mf) {
      const float* p = xb + (size_t)(mf * 16) * Ddim + k * 32 + lg * 8;
      float4 v0 = *(const float4*)p;
      float4 v1 = *(const float4*)(p + 4);
      u16x8 r;
      r[0] = f2bf(v0.x); r[1] = f2bf(v0.y); r[2] = f2bf(v0.z); r[3] = f2bf(v0.w);
      r[4] = f2bf(v1.x); r[5] = f2bf(v1.y); r[6] = f2bf(v1.z); r[7] = f2bf(v1.w);
      xf[k][mf] = r;
    }
  }

  f32x4 oacc[4][4];
  const f32x4 fz = {0.f, 0.f, 0.f, 0.f};
  #pragma unroll
  for (int mf = 0; mf < 4; ++mf)
    #pragma unroll
    for (int nf = 0; nf < 4; ++nf) oacc[mf][nf] = fz;

  // ---- prologue: stage chunk 0 into buf 0 ----
  {
    const unsigned short* src = wch + (size_t)(widx[0] * 32) * 16384 + tid * 8;
    unsigned short* l = lds + tid * 8;
    #pragma unroll
    for (int q = 0; q < 8; ++q) glds16(src + q * 2048, l + q * 2048);
  }
  __syncthreads();  // drains vmcnt -> buf0 ready

  for (int j = 0; j < total; ++j) {
    unsigned short* cur = lds + (j & 1) * 16384;
    unsigned short* nxt = lds + ((j & 1) ^ 1) * 16384;

    // issue next chunk (overlaps with stage-1 compute below)
    if (j + 1 < total) {
      int m2 = (j + 1) >> 5, hc2 = (j + 1) & 31;
      const unsigned short* src = wch + (size_t)(widx[m2] * 32 + hc2) * 16384 + tid * 8;
      unsigned short* l = nxt + tid * 8;
      #pragma unroll
      for (int q = 0; q < 8; ++q) glds16(src + q * 2048, l + q * 2048);
    }

    const int m = j >> 5, hc = j & 31;
    const float* b1g = (widx[m] < 4) ? (eb1 + widx[m] * Hdim) : sb1;
    const float wscale = wsc[m];

    // ---- stage 1: a1(64x32) = x @ W1chunk ----
    f32x4 a1[2];
    a1[0] = fz; a1[1] = fz;
    #pragma unroll
    for (int k = 0; k < 8; ++k) {
      u16x8 bf = *(const u16x8*)&cur[((k * 2 + wn) * 64 + lane) * 8];
      a1[0] = MFMA(xf[k][0], bf, a1[0]);
      a1[1] = MFMA(xf[k][1], bf, a1[1]);
    }
    float b1v = b1g[hc * 32 + wn * 16 + lr];
    #pragma unroll
    for (int mr = 0; mr < 2; ++mr)
      #pragma unroll
      for (int r = 0; r < 4; ++r)
        hid[(wm * 32 + mr * 16 + lg * 4 + r) * 40 + wn * 16 + lr] =
            f2bf(gelu_t(a1[mr][r] + b1v) * wscale);
    __syncthreads();

    // ---- stage 2: oacc += hid @ W2chunk (K=32) ----
    u16x8 ha[4], wb[4];
    #pragma unroll
    for (int mf = 0; mf < 4; ++mf)
      ha[mf] = *(const u16x8*)&hid[(mf * 16 + lr) * 40 + lg * 8];
    #pragma unroll
    for (int nf = 0; nf < 4; ++nf)
      wb[nf] = *(const u16x8*)&cur[8192 + ((wave * 4 + nf) * 64 + lane) * 8];
    #pragma unroll
    for (int mf = 0; mf < 4; ++mf)
      #pragma unroll
      for (int nf = 0; nf < 4; ++nf)
        oacc[mf][nf] = MFMA(ha[mf], wb[nf], oacc[mf][nf]);
    __syncthreads();
  }

  // ---- epilogue: bias + store (no atomics; block owns full 64x256 tile) ----
  float* og = out + ((size_t)b * LSEQ + t * 64) * Ddim;
  #pragma unroll
  for (int nf = 0; nf < 4; ++nf) {
    int dcol = wave * 64 + nf * 16 + lr;
    float bias = sb2[dcol];
    for (int m = 0; m < nm; ++m)
      if (widx[m] < 4) bias += wsc[m] * eb2[widx[m] * Ddim + dcol];
    #pragma unroll
    for (int mf = 0; mf < 4; ++mf)
      #pragma unroll
      for (int r = 0; r < 4; ++r)
        og[(size_t)(mf * 16 + lg * 4 + r) * Ddim + dcol] = oacc[mf][nf][r] + bias;
  }
}

// ---------------- launch ----------------

extern "C" void kernel_launch(void* const* d_in, const int* in_sizes, int n_in,
                              void* d_out, int out_size, void* d_ws, size_t ws_size,
                              hipStream_t stream) {
  const float* x      = (const float*)d_in[0];
  const float* tc     = (const float*)d_in[1];
  const float* gate_w = (const float*)d_in[2];
  const float* gate_b = (const float*)d_in[3];
  const float* tmod_w = (const float*)d_in[4];
  const float* tmod_b = (const float*)d_in[5];
  const float* ew1    = (const float*)d_in[6];
  const float* eb1    = (const float*)d_in[7];
  const float* ew2    = (const float*)d_in[8];
  const float* eb2    = (const float*)d_in[9];
  const float* sw1    = (const float*)d_in[10];
  const float* sb1    = (const float*)d_in[11];
  const float* sw2    = (const float*)d_in[12];
  const float* sb2    = (const float*)d_in[13];
  float* out = (float*)d_out;

  char* wsb = (char*)d_ws;
  float* ws_seg = (float*)wsb;                             // 8*3*256 f32
  float* ws_wbe = (float*)(wsb + 24576);                   // 8*4 f32
  unsigned short* wch = (unsigned short*)(wsb + 32768);    // [5][32][16384] u16 = 5.24 MB

  zero_seg<<<24, 256, 0, stream>>>(ws_seg);
  seg_reduce<<<dim3(24, 8), 256, 0, stream>>>(x, ws_seg);
  gate_kernel<<<1, 512, 0, stream>>>(ws_seg, tc, gate_w, gate_b, tmod_w, tmod_b, ws_wbe);
  prep_w1f_v2<<<dim3(32, 5), 256, 0, stream>>>(ew1, sw1, wch);
  prep_w2f_v2<<<dim3(32, 5), 256, 0, stream>>>(ew2, sw2, wch);
  moe_main<<<384, 256, 0, stream>>>(x, wch, eb1, sb1, eb2, sb2, ws_wbe, out);
}

// Round 5
// 280.143 us; speedup vs baseline: 1.5831x; 1.1179x over previous
//
#include <hip/hip_runtime.h>
#include <stdint.h>

#define Ddim 256
#define Hdim 1024
#define LSEQ 3072

typedef __bf16 bf16x8 __attribute__((ext_vector_type(8)));
typedef unsigned short u16x8 __attribute__((ext_vector_type(8)));
typedef float f32x4 __attribute__((ext_vector_type(4)));

#define MFMA(a, b, c) __builtin_amdgcn_mfma_f32_16x16x32_bf16( \
    __builtin_bit_cast(bf16x8, (a)), __builtin_bit_cast(bf16x8, (b)), (c), 0, 0, 0)

__device__ __forceinline__ unsigned short f2bf(float f) {
  unsigned int u = __float_as_uint(f);
  u = u + 0x7FFFu + ((u >> 16) & 1u);
  return (unsigned short)(u >> 16);
}

__device__ __forceinline__ float gelu_t(float x) {
  float t = 0.7978845608028654f * (x + 0.044715f * x * x * x);
  float e = __expf(2.0f * t);
  float th = 1.0f - 2.0f / (e + 1.0f);
  return 0.5f * x * (1.0f + th);
}

// async global->LDS, 16B/lane, 4KB per call at 256 threads
__device__ __forceinline__ void glds16(const unsigned short* g, unsigned short* l) {
  __builtin_amdgcn_global_load_lds(
      (const __attribute__((address_space(1))) unsigned int*)g,
      (__attribute__((address_space(3))) unsigned int*)l, 16, 0, 0);
}

// Active-MLP list for (batch b, segment seg)
__device__ __forceinline__ int gate_list(const float* __restrict__ wbe, int b, int seg,
                                         int* widx, float* wsc) {
  float wv0 = wbe[b * 4 + 0], wv1 = wbe[b * 4 + 1];
  float wv2 = wbe[b * 4 + 2], wv3 = wbe[b * 4 + 3];
  int nm = 0;
  widx[nm] = 4; wsc[nm] = 1.0f; ++nm;                       // shared MLP
  if (wv0 > 0.0f) { widx[nm] = 0; wsc[nm] = wv0; ++nm; }
  if (wv1 > 0.0f && seg != 1) { widx[nm] = 1; wsc[nm] = wv1; ++nm; }  // head|prop
  if (wv2 > 0.0f && seg != 0) { widx[nm] = 2; wsc[nm] = wv2; ++nm; }  // wrist|prop
  if (wv3 > 0.0f && nm < 3) { widx[nm] = 3; wsc[nm] = wv3; ++nm; }
  return nm;
}

// ---------------- gating ----------------

// grid (24, 8): partial sums, no atomics. part[(b*24+lb)*256 + d]
__global__ void seg_reduce(const float* __restrict__ x, float* __restrict__ part) {
  int lb = blockIdx.x, b = blockIdx.y, tid = threadIdx.x;
  const float* xg = x + ((size_t)b * LSEQ + (size_t)lb * 128) * Ddim + tid;
  float s = 0.0f;
  #pragma unroll 8
  for (int r = 0; r < 128; ++r) s += xg[(size_t)r * Ddim];
  part[(size_t)(b * 24 + lb) * 256 + tid] = s;
}

// 1 block, 512 threads: wave w handles batch w.
__global__ void gate_kernel(const float* __restrict__ part, const float* __restrict__ tc,
                            const float* __restrict__ gw, const float* __restrict__ gb,
                            const float* __restrict__ tw, const float* __restrict__ tb,
                            float* __restrict__ wbe) {
  int b = threadIdx.x >> 6, lane = threadIdx.x & 63;
  float pl[4] = {0.f, 0.f, 0.f, 0.f};
  for (int d = lane; d < 256; d += 64) {
    float Sh = 0.f, Sw = 0.f, Sp = 0.f;
    #pragma unroll
    for (int lb = 0; lb < 8; ++lb)  Sh += part[(size_t)(b * 24 + lb) * 256 + d];
    #pragma unroll
    for (int lb = 8; lb < 16; ++lb) Sw += part[(size_t)(b * 24 + lb) * 256 + d];
    #pragma unroll
    for (int lb = 16; lb < 24; ++lb) Sp += part[(size_t)(b * 24 + lb) * 256 + d];
    float vF = (Sh + Sw + Sp) * (1.0f / 3072.0f);
    float vH = (Sh + Sp) * (1.0f / 2048.0f);
    float vW = (Sw + Sp) * (1.0f / 2048.0f);
    #pragma unroll
    for (int e = 0; e < 4; ++e)
      pl[e] += vF * gw[d * 4 + e] + vH * gw[(256 + d) * 4 + e] + vW * gw[(512 + d) * 4 + e];
  }
  float pm[8] = {0.f, 0.f, 0.f, 0.f, 0.f, 0.f, 0.f, 0.f};
  for (int d = lane; d < 256; d += 64) {
    float t = tc[b * 256 + d];
    float s = t / (1.0f + __expf(-t));
    #pragma unroll
    for (int j = 0; j < 8; ++j) pm[j] += s * tw[d * 8 + j];
  }
  #pragma unroll
  for (int off = 32; off > 0; off >>= 1) {
    #pragma unroll
    for (int e = 0; e < 4; ++e) pl[e] += __shfl_down(pl[e], off);
    #pragma unroll
    for (int j = 0; j < 8; ++j) pm[j] += __shfl_down(pm[j], off);
  }
  if (lane == 0) {
    #pragma unroll
    for (int j = 0; j < 8; ++j) pm[j] += tb[j];
    float lg[4], sc[4];
    #pragma unroll
    for (int e = 0; e < 4; ++e) lg[e] = (pl[e] + gb[e]) * (1.0f + pm[e]) + pm[4 + e];
    float mx = fmaxf(fmaxf(lg[0], lg[1]), fmaxf(lg[2], lg[3]));
    float s = 0.0f;
    #pragma unroll
    for (int e = 0; e < 4; ++e) { sc[e] = __expf(lg[e] - mx); s += sc[e]; }
    #pragma unroll
    for (int e = 0; e < 4; ++e) sc[e] /= s;
    int i1 = 0;
    #pragma unroll
    for (int e = 1; e < 4; ++e) if (sc[e] > sc[i1]) i1 = e;
    int i2 = (i1 == 0) ? 1 : 0;
    #pragma unroll
    for (int e = 0; e < 4; ++e) if (e != i1 && sc[e] > sc[i2]) i2 = e;
    float den = sc[i1] + sc[i2] + 1e-8f;
    #pragma unroll
    for (int e = 0; e < 4; ++e)
      wbe[b * 4 + e] = (e == i1) ? sc[i1] / den : ((e == i2) ? sc[i2] / den : 0.0f);
  }
}

// ---------------- weight prep (fused): f32 -> bf16 fragment chunks ----------------
// wch[id][hc 32][16384 u16]: [0,8192) = W1 frags [k 8][hg 2][lane 64][8]
//                            [8192,16384) = W2 frags [dg 16][lane 64][8]
__global__ void prep_weights(const float* __restrict__ ew1, const float* __restrict__ sw1,
                             const float* __restrict__ ew2, const float* __restrict__ sw2,
                             unsigned short* __restrict__ wch) {
  int hc = blockIdx.x, id = blockIdx.y;
  int tid = threadIdx.x;
  int lane = tid & 63, lr = lane & 15, lg = lane >> 4;
  int h0 = hc * 32;
  if (blockIdx.z == 0) {
    const float* src = (id < 4) ? (ew1 + (size_t)id * Ddim * Hdim) : sw1;  // [256][1024]
    __shared__ float tile[256 * 33];
    #pragma unroll
    for (int p = 0; p < 8; ++p) {
      int row = p * 32 + (tid >> 3);
      int c = (tid & 7) * 4;
      float4 v = *(const float4*)&src[(size_t)row * Hdim + h0 + c];
      tile[row * 33 + c] = v.x; tile[row * 33 + c + 1] = v.y;
      tile[row * 33 + c + 2] = v.z; tile[row * 33 + c + 3] = v.w;
    }
    __syncthreads();
    unsigned short* dst = wch + ((size_t)(id * 32 + hc)) * 16384;
    #pragma unroll
    for (int p = 0; p < 4; ++p) {
      int f = tid + p * 256;
      int hg = (f >> 6) & 1, k = f >> 7;
      u16x8 r;
      #pragma unroll
      for (int j = 0; j < 8; ++j) r[j] = f2bf(tile[(k * 32 + lg * 8 + j) * 33 + hg * 16 + lr]);
      *(u16x8*)&dst[(size_t)f * 8] = r;
    }
  } else {
    const float* src = (id < 4) ? (ew2 + (size_t)id * Hdim * Ddim) : sw2;  // [1024][256]
    __shared__ float tile2[32 * 264];
    #pragma unroll
    for (int p = 0; p < 8; ++p) {
      int hh = p * 4 + (tid >> 6);
      int c = (tid & 63) * 4;
      float4 v = *(const float4*)&src[(size_t)(h0 + hh) * Ddim + c];
      int ci = c + (c >> 5);
      tile2[hh * 264 + ci] = v.x; tile2[hh * 264 + ci + 1] = v.y;
      tile2[hh * 264 + ci + 2] = v.z; tile2[hh * 264 + ci + 3] = v.w;
    }
    __syncthreads();
    unsigned short* dst = wch + ((size_t)(id * 32 + hc)) * 16384 + 8192;
    #pragma unroll
    for (int p = 0; p < 4; ++p) {
      int f = tid + p * 256;
      int dg = f >> 6;
      u16x8 r;
      #pragma unroll
      for (int j = 0; j < 8; ++j) {
        int c = dg * 16 + lr;
        r[j] = f2bf(tile2[(lg * 8 + j) * 264 + c + (c >> 5)]);
      }
      *(u16x8*)&dst[(size_t)f * 8] = r;
    }
  }
}

// ---------------- main fused MoE-MLP kernel ----------------
// Grid 384 = (b 8) x (t 48). 256 threads = 4 waves. Per iteration: W1 16KB chunk
// staged via global_load_lds (2-phase counted pipeline: issue at top, vmcnt(0)
// only at iter END), W2 fragments direct global->reg double-buffered (T14),
// mid-iter raw barrier drains lgkmcnt only (hid visibility, vmcnt in flight).
__global__ __launch_bounds__(256, 2) void moe_main(
    const float* __restrict__ x, const unsigned short* __restrict__ wch,
    const float* __restrict__ eb1, const float* __restrict__ sb1,
    const float* __restrict__ eb2, const float* __restrict__ sb2,
    const float* __restrict__ wbe, float* __restrict__ out) {
  __shared__ __align__(16) unsigned short lds[2 * 8192 + 64 * 40];
  unsigned short* const bufA = lds;
  unsigned short* const bufB = lds + 8192;
  unsigned short* const hid = lds + 16384;  // [64][40]

  const int i = blockIdx.x;
  const int b = i & 7, t = i >> 3;
  const int tid = threadIdx.x;
  const int wave = tid >> 6, lane = tid & 63;
  const int lr = lane & 15, lg = lane >> 4;
  const int wm = wave >> 1, wn = wave & 1;
  const int seg = t >> 4;

  int widx[3]; float wsc[3];
  const int nm = gate_list(wbe, b, seg, widx, wsc);
  const int total = nm * 32;
  // scalarized lookup (avoid runtime-indexed arrays -> scratch, rule #20)
  const int wi0 = widx[0], wi1 = (nm > 1) ? widx[1] : widx[0],
            wi2 = (nm > 2) ? widx[2] : wi1;
  const float sc0 = wsc[0], sc1 = (nm > 1) ? wsc[1] : 0.f, sc2 = (nm > 2) ? wsc[2] : 0.f;

  // ---- x A-fragments global->reg (f32 -> bf16), reused across all iterations ----
  u16x8 xf[8][2];
  const float* xb = x + ((size_t)(b * LSEQ + t * 64 + wm * 32 + lr)) * Ddim;
  #pragma unroll
  for (int k = 0; k < 8; ++k) {
    #pragma unroll
    for (int mf = 0; mf < 2; ++mf) {
      const float* p = xb + (size_t)(mf * 16) * Ddim + k * 32 + lg * 8;
      float4 v0 = *(const float4*)p;
      float4 v1 = *(const float4*)(p + 4);
      u16x8 r;
      r[0] = f2bf(v0.x); r[1] = f2bf(v0.y); r[2] = f2bf(v0.z); r[3] = f2bf(v0.w);
      r[4] = f2bf(v1.x); r[5] = f2bf(v1.y); r[6] = f2bf(v1.z); r[7] = f2bf(v1.w);
      xf[k][mf] = r;
    }
  }

  f32x4 oacc[4][4];
  const f32x4 fz = {0.f, 0.f, 0.f, 0.f};
  #pragma unroll
  for (int mf = 0; mf < 4; ++mf)
    #pragma unroll
    for (int nf = 0; nf < 4; ++nf) oacc[mf][nf] = fz;

  u16x8 wbA[4], wbB[4];

  // ---- prologue: stage chunk 0 (W1->bufA, W2->wbA) ----
  {
    const unsigned short* c0 = wch + (size_t)(wi0 * 32) * 16384;
    #pragma unroll
    for (int q = 0; q < 4; ++q) glds16(c0 + tid * 8 + q * 2048, bufA + tid * 8 + q * 2048);
    const unsigned short* w2c = c0 + 8192 + ((size_t)(wave * 4) * 64 + lane) * 8;
    #pragma unroll
    for (int nf = 0; nf < 4; ++nf) wbA[nf] = *(const u16x8*)(w2c + nf * 512);
  }
  asm volatile("s_waitcnt vmcnt(0)" ::: "memory");
  __builtin_amdgcn_s_barrier();
  __builtin_amdgcn_sched_barrier(0);

#define ITER(J, CUR, NXT, WBU, WBP)                                               \
  {                                                                               \
    const int jn = ((J) + 1 < total) ? (J) + 1 : total - 1;                       \
    const int mN = jn >> 5, hcN = jn & 31;                                        \
    const int idN = (mN == 0) ? wi0 : ((mN == 1) ? wi1 : wi2);                    \
    const unsigned short* cbN = wch + (size_t)(idN * 32 + hcN) * 16384;           \
    _Pragma("unroll")                                                             \
    for (int q = 0; q < 4; ++q)                                                   \
      glds16(cbN + tid * 8 + q * 2048, (NXT) + tid * 8 + q * 2048);               \
    const unsigned short* w2n = cbN + 8192 + ((size_t)(wave * 4) * 64 + lane) * 8;\
    _Pragma("unroll")                                                             \
    for (int nf = 0; nf < 4; ++nf) (WBP)[nf] = *(const u16x8*)(w2n + nf * 512);   \
    const int mC = (J) >> 5, hcC = (J) & 31;                                      \
    const int idC = (mC == 0) ? wi0 : ((mC == 1) ? wi1 : wi2);                    \
    const float wscale = (mC == 0) ? sc0 : ((mC == 1) ? sc1 : sc2);               \
    const float* b1g = (idC < 4) ? (eb1 + idC * Hdim) : sb1;                      \
    float b1v = b1g[hcC * 32 + wn * 16 + lr];                                     \
    f32x4 a1[2]; a1[0] = fz; a1[1] = fz;                                          \
    __builtin_amdgcn_s_setprio(1);                                                \
    _Pragma("unroll")                                                             \
    for (int k = 0; k < 8; ++k) {                                                 \
      u16x8 bf = *(const u16x8*)&(CUR)[((k * 2 + wn) * 64 + lane) * 8];           \
      a1[0] = MFMA(xf[k][0], bf, a1[0]);                                          \
      a1[1] = MFMA(xf[k][1], bf, a1[1]);                                          \
    }                                                                             \
    __builtin_amdgcn_s_setprio(0);                                                \
    _Pragma("unroll")                                                             \
    for (int mr = 0; mr < 2; ++mr)                                                \
      _Pragma("unroll")                                                           \
      for (int r = 0; r < 4; ++r)                                                 \
        hid[(wm * 32 + mr * 16 + lg * 4 + r) * 40 + wn * 16 + lr] =               \
            f2bf(gelu_t(a1[mr][r] + b1v) * wscale);                               \
    asm volatile("s_waitcnt lgkmcnt(0)" ::: "memory");                            \
    __builtin_amdgcn_s_barrier();                                                 \
    __builtin_amdgcn_sched_barrier(0);                                            \
    u16x8 ha[4];                                                                  \
    _Pragma("unroll")                                                             \
    for (int mf = 0; mf < 4; ++mf)                                                \
      ha[mf] = *(const u16x8*)&hid[(mf * 16 + lr) * 40 + lg * 8];                 \
    __builtin_amdgcn_s_setprio(1);                                                \
    _Pragma("unroll")                                                             \
    for (int mf = 0; mf < 4; ++mf)                                                \
      _Pragma("unroll")                                                           \
      for (int nf = 0; nf < 4; ++nf)                                              \
        oacc[mf][nf] = MFMA(ha[mf], (WBU)[nf], oacc[mf][nf]);                     \
    __builtin_amdgcn_s_setprio(0);                                                \
    asm volatile("s_waitcnt vmcnt(0)" ::: "memory");                              \
    __builtin_amdgcn_s_barrier();                                                 \
    __builtin_amdgcn_sched_barrier(0);                                            \
  }

  for (int j = 0; j < total; j += 2) {
    ITER(j, bufA, bufB, wbA, wbB);
    ITER(j + 1, bufB, bufA, wbB, wbA);
  }
#undef ITER

  // ---- epilogue: bias + store (block owns full 64x256 tile) ----
  float* og = out + ((size_t)b * LSEQ + t * 64) * Ddim;
  #pragma unroll
  for (int nf = 0; nf < 4; ++nf) {
    int dcol = wave * 64 + nf * 16 + lr;
    float bias = sb2[dcol];
    if (wi0 < 4) bias += sc0 * eb2[wi0 * Ddim + dcol];
    if (nm > 1 && wi1 < 4) bias += sc1 * eb2[wi1 * Ddim + dcol];
    if (nm > 2 && wi2 < 4) bias += sc2 * eb2[wi2 * Ddim + dcol];
    #pragma unroll
    for (int mf = 0; mf < 4; ++mf)
      #pragma unroll
      for (int r = 0; r < 4; ++r)
        og[(size_t)(mf * 16 + lg * 4 + r) * Ddim + dcol] = oacc[mf][nf][r] + bias;
  }
}

// ---------------- launch ----------------

extern "C" void kernel_launch(void* const* d_in, const int* in_sizes, int n_in,
                              void* d_out, int out_size, void* d_ws, size_t ws_size,
                              hipStream_t stream) {
  const float* x      = (const float*)d_in[0];
  const float* tc     = (const float*)d_in[1];
  const float* gate_w = (const float*)d_in[2];
  const float* gate_b = (const float*)d_in[3];
  const float* tmod_w = (const float*)d_in[4];
  const float* tmod_b = (const float*)d_in[5];
  const float* ew1    = (const float*)d_in[6];
  const float* eb1    = (const float*)d_in[7];
  const float* ew2    = (const float*)d_in[8];
  const float* eb2    = (const float*)d_in[9];
  const float* sw1    = (const float*)d_in[10];
  const float* sb1    = (const float*)d_in[11];
  const float* sw2    = (const float*)d_in[12];
  const float* sb2    = (const float*)d_in[13];
  float* out = (float*)d_out;

  char* wsb = (char*)d_ws;
  float* ws_part = (float*)wsb;                            // 8*24*256 f32 = 196608 B
  float* ws_wbe  = (float*)(wsb + 200704);                 // 32 f32
  unsigned short* wch = (unsigned short*)(wsb + 204800);   // [5][32][16384] u16 = 5.24 MB

  seg_reduce<<<dim3(24, 8), 256, 0, stream>>>(x, ws_part);
  gate_kernel<<<1, 512, 0, stream>>>(ws_part, tc, gate_w, gate_b, tmod_w, tmod_b, ws_wbe);
  prep_weights<<<dim3(32, 5, 2), 256, 0, stream>>>(ew1, sw1, ew2, sw2, wch);
  moe_main<<<384, 256, 0, stream>>>(x, wch, eb1, sb1, eb2, sb2, ws_wbe, out);
}

// Round 6
// 270.250 us; speedup vs baseline: 1.6410x; 1.0366x over previous
//
#include <hip/hip_runtime.h>
#include <stdint.h>

#define Ddim 256
#define Hdim 1024
#define LSEQ 3072

typedef __bf16 bf16x8 __attribute__((ext_vector_type(8)));
typedef unsigned short u16x8 __attribute__((ext_vector_type(8)));
typedef float f32x4 __attribute__((ext_vector_type(4)));

#define MFMA(a, b, c) __builtin_amdgcn_mfma_f32_16x16x32_bf16( \
    __builtin_bit_cast(bf16x8, (a)), __builtin_bit_cast(bf16x8, (b)), (c), 0, 0, 0)

__device__ __forceinline__ unsigned short f2bf(float f) {
  unsigned int u = __float_as_uint(f);
  u = u + 0x7FFFu + ((u >> 16) & 1u);
  return (unsigned short)(u >> 16);
}

__device__ __forceinline__ float gelu_t(float x) {
  float t = 0.7978845608028654f * (x + 0.044715f * x * x * x);
  float e = __expf(2.0f * t);
  float th = 1.0f - 2.0f / (e + 1.0f);
  return 0.5f * x * (1.0f + th);
}

// async global->LDS, 16B/lane, 4KB per call at 256 threads
__device__ __forceinline__ void glds16(const unsigned short* g, unsigned short* l) {
  __builtin_amdgcn_global_load_lds(
      (const __attribute__((address_space(1))) unsigned int*)g,
      (__attribute__((address_space(3))) unsigned int*)l, 16, 0, 0);
}

// Butterfly-uniform gate evaluation: every lane of every wave ends with the
// same wi0..2 / sc0..2 / nm. Reads 24KB of partials (L2-hot) + tiny weights.
__device__ __forceinline__ void gate_eval(
    const float* __restrict__ part, const float* __restrict__ tc,
    const float* __restrict__ gw, const float* __restrict__ gb,
    const float* __restrict__ tw, const float* __restrict__ tb,
    int b, int seg, int& nm, int& wi0, int& wi1, int& wi2,
    float& sc0, float& sc1, float& sc2) {
  int lane = threadIdx.x & 63;
  float pl[4] = {0.f, 0.f, 0.f, 0.f};
  float pm[8] = {0.f, 0.f, 0.f, 0.f, 0.f, 0.f, 0.f, 0.f};
  for (int d = lane; d < 256; d += 64) {
    float Sh = 0.f, Sw = 0.f, Sp = 0.f;
    #pragma unroll
    for (int lb = 0; lb < 8; ++lb)  Sh += part[(size_t)(b * 24 + lb) * 256 + d];
    #pragma unroll
    for (int lb = 8; lb < 16; ++lb) Sw += part[(size_t)(b * 24 + lb) * 256 + d];
    #pragma unroll
    for (int lb = 16; lb < 24; ++lb) Sp += part[(size_t)(b * 24 + lb) * 256 + d];
    float vF = (Sh + Sw + Sp) * (1.0f / 3072.0f);
    float vH = (Sh + Sp) * (1.0f / 2048.0f);
    float vW = (Sw + Sp) * (1.0f / 2048.0f);
    #pragma unroll
    for (int e = 0; e < 4; ++e)
      pl[e] += vF * gw[d * 4 + e] + vH * gw[(256 + d) * 4 + e] + vW * gw[(512 + d) * 4 + e];
    float t = tc[b * 256 + d];
    float s = t / (1.0f + __expf(-t));
    #pragma unroll
    for (int j = 0; j < 8; ++j) pm[j] += s * tw[d * 8 + j];
  }
  #pragma unroll
  for (int off = 1; off < 64; off <<= 1) {
    #pragma unroll
    for (int e = 0; e < 4; ++e) pl[e] += __shfl_xor(pl[e], off);
    #pragma unroll
    for (int j = 0; j < 8; ++j) pm[j] += __shfl_xor(pm[j], off);
  }
  #pragma unroll
  for (int j = 0; j < 8; ++j) pm[j] += tb[j];
  float lg[4], sc[4];
  #pragma unroll
  for (int e = 0; e < 4; ++e) lg[e] = (pl[e] + gb[e]) * (1.0f + pm[e]) + pm[4 + e];
  float mx = fmaxf(fmaxf(lg[0], lg[1]), fmaxf(lg[2], lg[3]));
  float s = 0.0f;
  #pragma unroll
  for (int e = 0; e < 4; ++e) { sc[e] = __expf(lg[e] - mx); s += sc[e]; }
  #pragma unroll
  for (int e = 0; e < 4; ++e) sc[e] /= s;
  int i1 = 0;
  #pragma unroll
  for (int e = 1; e < 4; ++e) if (sc[e] > sc[i1]) i1 = e;
  int i2 = (i1 == 0) ? 1 : 0;
  #pragma unroll
  for (int e = 0; e < 4; ++e) if (e != i1 && sc[e] > sc[i2]) i2 = e;
  float den = sc[i1] + sc[i2] + 1e-8f;
  float w0 = 0.f, w1 = 0.f, w2v = 0.f, w3 = 0.f;
  #pragma unroll
  for (int e = 0; e < 4; ++e) {
    float v = (e == i1) ? sc[i1] / den : ((e == i2) ? sc[i2] / den : 0.0f);
    if (e == 0) w0 = v; else if (e == 1) w1 = v; else if (e == 2) w2v = v; else w3 = v;
  }
  nm = 0;
  int widx[3]; float wsc[3];
  widx[nm] = 4; wsc[nm] = 1.0f; ++nm;
  if (w0 > 0.0f) { widx[nm] = 0; wsc[nm] = w0; ++nm; }
  if (w1 > 0.0f && seg != 1) { widx[nm] = 1; wsc[nm] = w1; ++nm; }
  if (w2v > 0.0f && seg != 0) { widx[nm] = 2; wsc[nm] = w2v; ++nm; }
  if (w3 > 0.0f && nm < 3) { widx[nm] = 3; wsc[nm] = w3; ++nm; }
  wi0 = widx[0];
  wi1 = (nm > 1) ? widx[1] : widx[0];
  wi2 = (nm > 2) ? widx[2] : wi1;
  sc0 = wsc[0];
  sc1 = (nm > 1) ? wsc[1] : 0.f;
  sc2 = (nm > 2) ? wsc[2] : 0.f;
}

// ---------------- K1: fused seg partial-sums + weight prep ----------------
// blocks 0..191: seg_reduce partials; blocks 192..511: prep chunks.
// wch[id][hc 32][16384 u16]: [0,8192) W1 frags [k 8][hg 2][lane 64][8],
//                            [8192,16384) W2 frags [dg 16][lane 64][8]
__global__ void k1_prep(const float* __restrict__ x, float* __restrict__ part,
                        const float* __restrict__ ew1, const float* __restrict__ sw1,
                        const float* __restrict__ ew2, const float* __restrict__ sw2,
                        unsigned short* __restrict__ wch) {
  __shared__ float tile[8448];
  int i = blockIdx.x, tid = threadIdx.x;
  if (i < 192) {
    int lb = i % 24, b = i / 24;
    const float* xg = x + ((size_t)b * LSEQ + (size_t)lb * 128) * Ddim + tid;
    float s = 0.0f;
    #pragma unroll 8
    for (int r = 0; r < 128; ++r) s += xg[(size_t)r * Ddim];
    part[(size_t)(b * 24 + lb) * 256 + tid] = s;
    return;
  }
  int pid = i - 192;
  int z = pid / 160, rem = pid % 160;
  int id = rem / 32, hc = rem % 32;
  int lane = tid & 63, lr = lane & 15, lg = lane >> 4;
  int h0 = hc * 32;
  if (z == 0) {
    const float* src = (id < 4) ? (ew1 + (size_t)id * Ddim * Hdim) : sw1;  // [256][1024]
    #pragma unroll
    for (int p = 0; p < 8; ++p) {
      int row = p * 32 + (tid >> 3);
      int c = (tid & 7) * 4;
      float4 v = *(const float4*)&src[(size_t)row * Hdim + h0 + c];
      tile[row * 33 + c] = v.x; tile[row * 33 + c + 1] = v.y;
      tile[row * 33 + c + 2] = v.z; tile[row * 33 + c + 3] = v.w;
    }
    __syncthreads();
    unsigned short* dst = wch + ((size_t)(id * 32 + hc)) * 16384;
    #pragma unroll
    for (int p = 0; p < 4; ++p) {
      int f = tid + p * 256;
      int hg = (f >> 6) & 1, k = f >> 7;
      u16x8 r;
      #pragma unroll
      for (int j = 0; j < 8; ++j) r[j] = f2bf(tile[(k * 32 + lg * 8 + j) * 33 + hg * 16 + lr]);
      *(u16x8*)&dst[(size_t)f * 8] = r;
    }
  } else {
    const float* src = (id < 4) ? (ew2 + (size_t)id * Hdim * Ddim) : sw2;  // [1024][256]
    #pragma unroll
    for (int p = 0; p < 8; ++p) {
      int hh = p * 4 + (tid >> 6);
      int c = (tid & 63) * 4;
      float4 v = *(const float4*)&src[(size_t)(h0 + hh) * Ddim + c];
      int ci = c + (c >> 5);
      tile[hh * 264 + ci] = v.x; tile[hh * 264 + ci + 1] = v.y;
      tile[hh * 264 + ci + 2] = v.z; tile[hh * 264 + ci + 3] = v.w;
    }
    __syncthreads();
    unsigned short* dst = wch + ((size_t)(id * 32 + hc)) * 16384 + 8192;
    #pragma unroll
    for (int p = 0; p < 4; ++p) {
      int f = tid + p * 256;
      int dg = f >> 6;
      u16x8 r;
      #pragma unroll
      for (int j = 0; j < 8; ++j) {
        int c = dg * 16 + lr;
        r[j] = f2bf(tile[(lg * 8 + j) * 264 + c + (c >> 5)]);
      }
      *(u16x8*)&dst[(size_t)f * 8] = r;
    }
  }
}

// ---------------- K2: main fused MoE-MLP kernel ----------------
// Grid 768 = (b 8) x (q 2) x (t 48). q = K-split half (16 h-chunks each).
// Depth-2 counted pipeline: 3 W1 LDS bufs, glds(j+2) at iter top, W2+b1 in
// regs same-iter (issued BEFORE glds so their auto-waits never drain the
// prefetch), manual vmcnt(18) before stage1, raw barriers (no vmcnt drain).
__global__ __launch_bounds__(256, 2) void moe_main(
    const float* __restrict__ x, const unsigned short* __restrict__ wch,
    const float* __restrict__ eb1, const float* __restrict__ sb1,
    const float* __restrict__ eb2, const float* __restrict__ sb2,
    const float* __restrict__ part, const float* __restrict__ tc,
    const float* __restrict__ gw, const float* __restrict__ gb,
    const float* __restrict__ tw, const float* __restrict__ tb,
    unsigned short* __restrict__ kpart, float* __restrict__ out) {
  __shared__ __align__(16) unsigned short lds[3 * 8192 + 64 * 40];
  unsigned short* const hid = lds + 3 * 8192;  // [64][40]

  const int i = blockIdx.x;
  const int b = i & 7, q = (i >> 3) & 1, t = i >> 4;
  const int tid = threadIdx.x;
  const int wave = tid >> 6, lane = tid & 63;
  const int lr = lane & 15, lg = lane >> 4;
  const int wm = wave >> 1, wn = wave & 1;
  const int seg = t >> 4;

  int nm, wi0, wi1, wi2;
  float sc0, sc1, sc2;
  gate_eval(part, tc, gw, gb, tw, tb, b, seg, nm, wi0, wi1, wi2, sc0, sc1, sc2);
  const int total = nm * 16;

  // ---- x A-fragments global->reg (f32 -> bf16) ----
  u16x8 xf[8][2];
  const float* xb = x + ((size_t)(b * LSEQ + t * 64 + wm * 32 + lr)) * Ddim;
  #pragma unroll
  for (int k = 0; k < 8; ++k) {
    #pragma unroll
    for (int mf = 0; mf < 2; ++mf) {
      const float* p = xb + (size_t)(mf * 16) * Ddim + k * 32 + lg * 8;
      float4 v0 = *(const float4*)p;
      float4 v1 = *(const float4*)(p + 4);
      u16x8 r;
      r[0] = f2bf(v0.x); r[1] = f2bf(v0.y); r[2] = f2bf(v0.z); r[3] = f2bf(v0.w);
      r[4] = f2bf(v1.x); r[5] = f2bf(v1.y); r[6] = f2bf(v1.z); r[7] = f2bf(v1.w);
      xf[k][mf] = r;
    }
  }

  f32x4 oacc[4][4];
  const f32x4 fz = {0.f, 0.f, 0.f, 0.f};
  #pragma unroll
  for (int mf = 0; mf < 4; ++mf)
    #pragma unroll
    for (int nf = 0; nf < 4; ++nf) oacc[mf][nf] = fz;

  unsigned short* p0 = lds;
  unsigned short* p1 = lds + 8192;
  unsigned short* p2 = lds + 16384;

  // chunk index helper: iter j -> (id, hc)
  // id = (j>>4)==0 ? wi0 : ==1 ? wi1 : wi2 ; hc = q*16 + (j&15)
  // ---- prologue: glds(0)->p0, glds(1)->p1 ----
  {
    const unsigned short* c0 = wch + (size_t)(wi0 * 32 + q * 16) * 16384;
    #pragma unroll
    for (int qq = 0; qq < 4; ++qq) glds16(c0 + tid * 8 + qq * 2048, p0 + tid * 8 + qq * 2048);
    int j1 = (total > 1) ? 1 : 0;
    int id1 = (j1 >> 4) == 0 ? wi0 : wi1;
    const unsigned short* c1 = wch + (size_t)(id1 * 32 + q * 16 + (j1 & 15)) * 16384;
    #pragma unroll
    for (int qq = 0; qq < 4; ++qq) glds16(c1 + tid * 8 + qq * 2048, p1 + tid * 8 + qq * 2048);
  }
  asm volatile("s_waitcnt vmcnt(4)" ::: "memory");  // glds(0) complete (4 newer ok)
  __builtin_amdgcn_s_barrier();
  __builtin_amdgcn_sched_barrier(0);

  for (int j = 0; j < total; ++j) {
    const int m = j >> 4, hc = q * 16 + (j & 15);
    const int id = (m == 0) ? wi0 : ((m == 1) ? wi1 : wi2);
    const float wscale = (m == 0) ? sc0 : ((m == 1) ? sc1 : sc2);
    const unsigned short* cb = wch + (size_t)(id * 32 + hc) * 16384;

    // (1) current-iter reg loads FIRST (b1 then W2) so their auto-waits
    //     retire before the glds prefetches in the vmcnt FIFO.
    const float* b1g = (id < 4) ? (eb1 + id * Hdim) : sb1;
    float b1v = b1g[hc * 32 + wn * 16 + lr];
    u16x8 wbU[4];
    const unsigned short* w2c = cb + 8192 + ((size_t)(wave * 4) * 64 + lane) * 8;
    #pragma unroll
    for (int nf = 0; nf < 4; ++nf) wbU[nf] = *(const u16x8*)(w2c + nf * 512);
    __builtin_amdgcn_sched_barrier(0);

    // (2) depth-2 prefetch: glds(j+2) -> p2
    {
      int j2 = (j + 2 < total) ? j + 2 : total - 1;
      int m2 = j2 >> 4;
      int id2 = (m2 == 0) ? wi0 : ((m2 == 1) ? wi1 : wi2);
      const unsigned short* cb2 = wch + (size_t)(id2 * 32 + q * 16 + (j2 & 15)) * 16384;
      #pragma unroll
      for (int qq = 0; qq < 4; ++qq)
        glds16(cb2 + tid * 8 + qq * 2048, p2 + tid * 8 + qq * 2048);
    }
    __builtin_amdgcn_sched_barrier(0);

    // (3) wait for glds(j) only: 18 = 2 iters x 9 vmem ops issued after it
    asm volatile("s_waitcnt vmcnt(18)" ::: "memory");
    __builtin_amdgcn_sched_barrier(0);

    // ---- stage 1: a1 = x @ W1chunk ----
    f32x4 a1[2];
    a1[0] = fz; a1[1] = fz;
    __builtin_amdgcn_s_setprio(1);
    #pragma unroll
    for (int k = 0; k < 8; ++k) {
      u16x8 bf = *(const u16x8*)&p0[((k * 2 + wn) * 64 + lane) * 8];
      a1[0] = MFMA(xf[k][0], bf, a1[0]);
      a1[1] = MFMA(xf[k][1], bf, a1[1]);
    }
    __builtin_amdgcn_s_setprio(0);
    #pragma unroll
    for (int mr = 0; mr < 2; ++mr)
      #pragma unroll
      for (int r = 0; r < 4; ++r)
        hid[(wm * 32 + mr * 16 + lg * 4 + r) * 40 + wn * 16 + lr] =
            f2bf(gelu_t(a1[mr][r] + b1v) * wscale);
    asm volatile("s_waitcnt lgkmcnt(0)" ::: "memory");
    __builtin_amdgcn_s_barrier();
    __builtin_amdgcn_sched_barrier(0);

    // ---- stage 2: oacc += hid @ W2chunk ----
    u16x8 ha[4];
    #pragma unroll
    for (int mf = 0; mf < 4; ++mf)
      ha[mf] = *(const u16x8*)&hid[(mf * 16 + lr) * 40 + lg * 8];
    __builtin_amdgcn_s_setprio(1);
    #pragma unroll
    for (int mf = 0; mf < 4; ++mf)
      #pragma unroll
      for (int nf = 0; nf < 4; ++nf)
        oacc[mf][nf] = MFMA(ha[mf], wbU[nf], oacc[mf][nf]);
    __builtin_amdgcn_s_setprio(0);
    __builtin_amdgcn_s_barrier();   // raw: protects hid + buf rotation, no drain
    __builtin_amdgcn_sched_barrier(0);

    unsigned short* tmp = p0; p0 = p1; p1 = p2; p2 = tmp;
  }

  // ---- epilogue ----
  if (q == 0) {
    float* og = out + ((size_t)b * LSEQ + t * 64) * Ddim;
    #pragma unroll
    for (int nf = 0; nf < 4; ++nf) {
      int dcol = wave * 64 + nf * 16 + lr;
      float bias = sb2[dcol];
      if (wi0 < 4) bias += sc0 * eb2[wi0 * Ddim + dcol];
      if (nm > 1 && wi1 < 4) bias += sc1 * eb2[wi1 * Ddim + dcol];
      if (nm > 2 && wi2 < 4) bias += sc2 * eb2[wi2 * Ddim + dcol];
      #pragma unroll
      for (int mf = 0; mf < 4; ++mf)
        #pragma unroll
        for (int r = 0; r < 4; ++r)
          og[(size_t)(mf * 16 + lg * 4 + r) * Ddim + dcol] = oacc[mf][nf][r] + bias;
    }
  } else {
    unsigned short* pg = kpart + ((size_t)b * LSEQ + t * 64) * Ddim;
    #pragma unroll
    for (int nf = 0; nf < 4; ++nf) {
      int dcol = wave * 64 + nf * 16 + lr;
      #pragma unroll
      for (int mf = 0; mf < 4; ++mf)
        #pragma unroll
        for (int r = 0; r < 4; ++r)
          pg[(size_t)(mf * 16 + lg * 4 + r) * Ddim + dcol] = f2bf(oacc[mf][nf][r]);
    }
  }
}

// ---------------- K3: combine (out += bf16 partial) ----------------
__global__ void combine(const unsigned short* __restrict__ kpart, float* __restrict__ out) {
  size_t base = ((size_t)blockIdx.x * 256 + threadIdx.x) * 8;
  u16x8 p = *(const u16x8*)&kpart[base];
  float4 o0 = *(const float4*)&out[base];
  float4 o1 = *(const float4*)&out[base + 4];
  o0.x += __uint_as_float((unsigned)p[0] << 16);
  o0.y += __uint_as_float((unsigned)p[1] << 16);
  o0.z += __uint_as_float((unsigned)p[2] << 16);
  o0.w += __uint_as_float((unsigned)p[3] << 16);
  o1.x += __uint_as_float((unsigned)p[4] << 16);
  o1.y += __uint_as_float((unsigned)p[5] << 16);
  o1.z += __uint_as_float((unsigned)p[6] << 16);
  o1.w += __uint_as_float((unsigned)p[7] << 16);
  *(float4*)&out[base] = o0;
  *(float4*)&out[base + 4] = o1;
}

// ---------------- launch ----------------

extern "C" void kernel_launch(void* const* d_in, const int* in_sizes, int n_in,
                              void* d_out, int out_size, void* d_ws, size_t ws_size,
                              hipStream_t stream) {
  const float* x      = (const float*)d_in[0];
  const float* tc     = (const float*)d_in[1];
  const float* gate_w = (const float*)d_in[2];
  const float* gate_b = (const float*)d_in[3];
  const float* tmod_w = (const float*)d_in[4];
  const float* tmod_b = (const float*)d_in[5];
  const float* ew1    = (const float*)d_in[6];
  const float* eb1    = (const float*)d_in[7];
  const float* ew2    = (const float*)d_in[8];
  const float* eb2    = (const float*)d_in[9];
  const float* sw1    = (const float*)d_in[10];
  const float* sb1    = (const float*)d_in[11];
  const float* sw2    = (const float*)d_in[12];
  const float* sb2    = (const float*)d_in[13];
  float* out = (float*)d_out;

  char* wsb = (char*)d_ws;
  float* ws_part = (float*)wsb;                            // 8*24*256 f32 = 196608 B
  unsigned short* wch = (unsigned short*)(wsb + 196608);   // 5*32*16384 u16 = 10.49 MB
  unsigned short* kpart = (unsigned short*)(wsb + 196608 + 10485760);  // 6.29M u16 = 12.6 MB

  k1_prep<<<512, 256, 0, stream>>>(x, ws_part, ew1, sw1, ew2, sw2, wch);
  moe_main<<<768, 256, 0, stream>>>(x, wch, eb1, sb1, eb2, sb2, ws_part, tc,
                                    gate_w, gate_b, tmod_w, tmod_b, kpart, out);
  combine<<<3072, 256, 0, stream>>>(kpart, out);
}

// Round 7
// 266.742 us; speedup vs baseline: 1.6626x; 1.0132x over previous
//
#include <hip/hip_runtime.h>
#include <stdint.h>

#define Ddim 256
#define Hdim 1024
#define LSEQ 3072

typedef __bf16 bf16x8 __attribute__((ext_vector_type(8)));
typedef unsigned short u16x8 __attribute__((ext_vector_type(8)));
typedef float f32x4 __attribute__((ext_vector_type(4)));

#define MFMA(a, b, c) __builtin_amdgcn_mfma_f32_16x16x32_bf16( \
    __builtin_bit_cast(bf16x8, (a)), __builtin_bit_cast(bf16x8, (b)), (c), 0, 0, 0)

__device__ __forceinline__ unsigned short f2bf(float f) {
  unsigned int u = __float_as_uint(f);
  u = u + 0x7FFFu + ((u >> 16) & 1u);
  return (unsigned short)(u >> 16);
}

// async global->LDS, 16B/lane, 4KB per call at 256 threads
__device__ __forceinline__ void glds16(const unsigned short* g, unsigned short* l) {
  __builtin_amdgcn_global_load_lds(
      (const __attribute__((address_space(1))) unsigned int*)g,
      (__attribute__((address_space(3))) unsigned int*)l, 16, 0, 0);
}

// Butterfly-uniform gate evaluation: every lane ends with the same result.
__device__ __forceinline__ void gate_eval(
    const float* __restrict__ part, const float* __restrict__ tc,
    const float* __restrict__ gw, const float* __restrict__ gb,
    const float* __restrict__ tw, const float* __restrict__ tb,
    int b, int seg, int& nm, int& wi0, int& wi1, int& wi2,
    float& sc0, float& sc1, float& sc2) {
  int lane = threadIdx.x & 63;
  float pl[4] = {0.f, 0.f, 0.f, 0.f};
  float pm[8] = {0.f, 0.f, 0.f, 0.f, 0.f, 0.f, 0.f, 0.f};
  for (int d = lane; d < 256; d += 64) {
    float Sh = 0.f, Sw = 0.f, Sp = 0.f;
    #pragma unroll
    for (int lb = 0; lb < 8; ++lb)  Sh += part[(size_t)(b * 24 + lb) * 256 + d];
    #pragma unroll
    for (int lb = 8; lb < 16; ++lb) Sw += part[(size_t)(b * 24 + lb) * 256 + d];
    #pragma unroll
    for (int lb = 16; lb < 24; ++lb) Sp += part[(size_t)(b * 24 + lb) * 256 + d];
    float vF = (Sh + Sw + Sp) * (1.0f / 3072.0f);
    float vH = (Sh + Sp) * (1.0f / 2048.0f);
    float vW = (Sw + Sp) * (1.0f / 2048.0f);
    #pragma unroll
    for (int e = 0; e < 4; ++e)
      pl[e] += vF * gw[d * 4 + e] + vH * gw[(256 + d) * 4 + e] + vW * gw[(512 + d) * 4 + e];
    float t = tc[b * 256 + d];
    float s = t / (1.0f + __expf(-t));
    #pragma unroll
    for (int j = 0; j < 8; ++j) pm[j] += s * tw[d * 8 + j];
  }
  #pragma unroll
  for (int off = 1; off < 64; off <<= 1) {
    #pragma unroll
    for (int e = 0; e < 4; ++e) pl[e] += __shfl_xor(pl[e], off);
    #pragma unroll
    for (int j = 0; j < 8; ++j) pm[j] += __shfl_xor(pm[j], off);
  }
  #pragma unroll
  for (int j = 0; j < 8; ++j) pm[j] += tb[j];
  float lg[4], sc[4];
  #pragma unroll
  for (int e = 0; e < 4; ++e) lg[e] = (pl[e] + gb[e]) * (1.0f + pm[e]) + pm[4 + e];
  float mx = fmaxf(fmaxf(lg[0], lg[1]), fmaxf(lg[2], lg[3]));
  float s = 0.0f;
  #pragma unroll
  for (int e = 0; e < 4; ++e) { sc[e] = __expf(lg[e] - mx); s += sc[e]; }
  #pragma unroll
  for (int e = 0; e < 4; ++e) sc[e] /= s;
  int i1 = 0;
  #pragma unroll
  for (int e = 1; e < 4; ++e) if (sc[e] > sc[i1]) i1 = e;
  int i2 = (i1 == 0) ? 1 : 0;
  #pragma unroll
  for (int e = 0; e < 4; ++e) if (e != i1 && sc[e] > sc[i2]) i2 = e;
  float den = sc[i1] + sc[i2] + 1e-8f;
  float w0 = 0.f, w1 = 0.f, w2v = 0.f, w3 = 0.f;
  #pragma unroll
  for (int e = 0; e < 4; ++e) {
    float v = (e == i1) ? sc[i1] / den : ((e == i2) ? sc[i2] / den : 0.0f);
    if (e == 0) w0 = v; else if (e == 1) w1 = v; else if (e == 2) w2v = v; else w3 = v;
  }
  nm = 0;
  int widx[3]; float wsc[3];
  widx[nm] = 4; wsc[nm] = 1.0f; ++nm;
  if (w0 > 0.0f) { widx[nm] = 0; wsc[nm] = w0; ++nm; }
  if (w1 > 0.0f && seg != 1) { widx[nm] = 1; wsc[nm] = w1; ++nm; }
  if (w2v > 0.0f && seg != 0) { widx[nm] = 2; wsc[nm] = w2v; ++nm; }
  if (w3 > 0.0f && nm < 3) { widx[nm] = 3; wsc[nm] = w3; ++nm; }
  wi0 = widx[0];
  wi1 = (nm > 1) ? widx[1] : widx[0];
  wi2 = (nm > 2) ? widx[2] : wi1;
  sc0 = wsc[0];
  sc1 = (nm > 1) ? wsc[1] : 0.f;
  sc2 = (nm > 2) ? wsc[2] : 0.f;
}

// ---------------- K1: fused seg partial-sums + weight prep ----------------
__global__ void k1_prep(const float* __restrict__ x, float* __restrict__ part,
                        const float* __restrict__ ew1, const float* __restrict__ sw1,
                        const float* __restrict__ ew2, const float* __restrict__ sw2,
                        unsigned short* __restrict__ wch) {
  __shared__ float tile[8448];
  int i = blockIdx.x, tid = threadIdx.x;
  if (i < 192) {
    int lb = i % 24, b = i / 24;
    const float* xg = x + ((size_t)b * LSEQ + (size_t)lb * 128) * Ddim + tid;
    float s = 0.0f;
    #pragma unroll 8
    for (int r = 0; r < 128; ++r) s += xg[(size_t)r * Ddim];
    part[(size_t)(b * 24 + lb) * 256 + tid] = s;
    return;
  }
  int pid = i - 192;
  int z = pid / 160, rem = pid % 160;
  int id = rem / 32, hc = rem % 32;
  int lane = tid & 63, lr = lane & 15, lg = lane >> 4;
  int h0 = hc * 32;
  if (z == 0) {
    const float* src = (id < 4) ? (ew1 + (size_t)id * Ddim * Hdim) : sw1;  // [256][1024]
    #pragma unroll
    for (int p = 0; p < 8; ++p) {
      int row = p * 32 + (tid >> 3);
      int c = (tid & 7) * 4;
      float4 v = *(const float4*)&src[(size_t)row * Hdim + h0 + c];
      tile[row * 33 + c] = v.x; tile[row * 33 + c + 1] = v.y;
      tile[row * 33 + c + 2] = v.z; tile[row * 33 + c + 3] = v.w;
    }
    __syncthreads();
    unsigned short* dst = wch + ((size_t)(id * 32 + hc)) * 16384;
    #pragma unroll
    for (int p = 0; p < 4; ++p) {
      int f = tid + p * 256;
      int hg = (f >> 6) & 1, k = f >> 7;
      u16x8 r;
      #pragma unroll
      for (int j = 0; j < 8; ++j) r[j] = f2bf(tile[(k * 32 + lg * 8 + j) * 33 + hg * 16 + lr]);
      *(u16x8*)&dst[(size_t)f * 8] = r;
    }
  } else {
    const float* src = (id < 4) ? (ew2 + (size_t)id * Hdim * Ddim) : sw2;  // [1024][256]
    #pragma unroll
    for (int p = 0; p < 8; ++p) {
      int hh = p * 4 + (tid >> 6);
      int c = (tid & 63) * 4;
      float4 v = *(const float4*)&src[(size_t)(h0 + hh) * Ddim + c];
      int ci = c + (c >> 5);
      tile[hh * 264 + ci] = v.x; tile[hh * 264 + ci + 1] = v.y;
      tile[hh * 264 + ci + 2] = v.z; tile[hh * 264 + ci + 3] = v.w;
    }
    __syncthreads();
    unsigned short* dst = wch + ((size_t)(id * 32 + hc)) * 16384 + 8192;
    #pragma unroll
    for (int p = 0; p < 4; ++p) {
      int f = tid + p * 256;
      int dg = f >> 6;
      u16x8 r;
      #pragma unroll
      for (int j = 0; j < 8; ++j) {
        int c = dg * 16 + lr;
        r[j] = f2bf(tile[(lg * 8 + j) * 264 + c + (c >> 5)]);
      }
      *(u16x8*)&dst[(size_t)f * 8] = r;
    }
  }
}

// ---------------- K2: main fused MoE-MLP kernel ----------------
// Grid 384 = (b 8) x (t 48), b = i&7 pins batch b on XCD b; all blocks
// co-resident (2/CU LDS cap) -> per-XCD weight stream is L2-resident.
// Depth-2 counted pipeline: 3 W1 LDS bufs (glds j+2 ahead), b1/W2 regs
// double-buffered 1 ahead, vmcnt(20) = exactly last-2-iters in flight.
// Stage-1 uses SWAPPED mfma(W1,x) so gelu results are 4-consecutive-h
// per thread -> 2x ds_write_b64 into hid.
__global__ __launch_bounds__(256, 2) void moe_main(
    const float* __restrict__ x, const unsigned short* __restrict__ wch,
    const float* __restrict__ eb1, const float* __restrict__ sb1,
    const float* __restrict__ eb2, const float* __restrict__ sb2,
    const float* __restrict__ part, const float* __restrict__ tc,
    const float* __restrict__ gw, const float* __restrict__ gb,
    const float* __restrict__ tw, const float* __restrict__ tb,
    float* __restrict__ out) {
  __shared__ __align__(16) unsigned short lds[3 * 8192 + 64 * 44];
  unsigned short* const hid = lds + 3 * 8192;  // [64 tok][44 pitch]

  const int i = blockIdx.x;
  const int b = i & 7, t = i >> 3;
  const int tid = threadIdx.x;
  const int wave = tid >> 6, lane = tid & 63;
  const int lr = lane & 15, lg = lane >> 4;
  const int seg = t >> 4;

  int nm, wi0, wi1, wi2;
  float sc0, sc1, sc2;
  gate_eval(part, tc, gw, gb, tw, tb, b, seg, nm, wi0, wi1, wi2, sc0, sc1, sc2);
  const int total = nm * 32;

#define CHUNK_ID(JJ) ((((JJ) >> 5) == 0) ? wi0 : ((((JJ) >> 5) == 1) ? wi1 : wi2))
#define CHUNK_PTR(JJ) (wch + (size_t)(CHUNK_ID(JJ) * 32 + ((JJ) & 31)) * 16384)

  // ---- x B-fragments (swapped stage-1): tok = wave*16 + lr ----
  u16x8 xf[8];
  const float* xb = x + ((size_t)(b * LSEQ + t * 64 + wave * 16 + lr)) * Ddim;
  #pragma unroll
  for (int k = 0; k < 8; ++k) {
    const float* p = xb + k * 32 + lg * 8;
    float4 v0 = *(const float4*)p;
    float4 v1 = *(const float4*)(p + 4);
    u16x8 r;
    r[0] = f2bf(v0.x); r[1] = f2bf(v0.y); r[2] = f2bf(v0.z); r[3] = f2bf(v0.w);
    r[4] = f2bf(v1.x); r[5] = f2bf(v1.y); r[6] = f2bf(v1.z); r[7] = f2bf(v1.w);
    xf[k] = r;
  }

  f32x4 oacc[4][4];
  const f32x4 fz = {0.f, 0.f, 0.f, 0.f};
  #pragma unroll
  for (int mf = 0; mf < 4; ++mf)
    #pragma unroll
    for (int nf = 0; nf < 4; ++nf) oacc[mf][nf] = fz;

  unsigned short* c0 = lds;
  unsigned short* c1 = lds + 8192;
  unsigned short* c2 = lds + 16384;

  float4 b1A[2], b1B[2];
  u16x8 wbA[4], wbB[4];

  // ---- prologue: glds(0)->c0, glds(1)->c1, regs(0)->A ----
  {
    const unsigned short* cb0 = CHUNK_PTR(0);
    #pragma unroll
    for (int qq = 0; qq < 4; ++qq) glds16(cb0 + tid * 8 + qq * 2048, c0 + tid * 8 + qq * 2048);
    const int j1 = (total > 1) ? 1 : 0;
    const unsigned short* cb1 = CHUNK_PTR(j1);
    #pragma unroll
    for (int qq = 0; qq < 4; ++qq) glds16(cb1 + tid * 8 + qq * 2048, c1 + tid * 8 + qq * 2048);
    const float* b1g0 = (wi0 < 4) ? (eb1 + wi0 * Hdim) : sb1;
    b1A[0] = *(const float4*)&b1g0[lg * 4];
    b1A[1] = *(const float4*)&b1g0[16 + lg * 4];
    const unsigned short* w20 = cb0 + 8192 + ((size_t)((wave * 4) * 64 + lane)) * 8;
    #pragma unroll
    for (int nf = 0; nf < 4; ++nf) wbA[nf] = *(const u16x8*)(w20 + nf * 512);
  }
  asm volatile("s_waitcnt vmcnt(10)" ::: "memory");  // glds(0) complete
  __builtin_amdgcn_s_barrier();
  __builtin_amdgcn_sched_barrier(0);

#define ITER(J, CUR, NXT2, B1U, WBU, B1P, WBP)                                   \
  {                                                                              \
    /* (1) prefetch regs for iter J+1 (BEFORE glds so FIFO waits are clean) */   \
    const int jn = ((J) + 1 < total) ? (J) + 1 : total - 1;                      \
    const unsigned short* cbn = CHUNK_PTR(jn);                                   \
    const int idn = CHUNK_ID(jn);                                                \
    const float* b1gn = (idn < 4) ? (eb1 + idn * Hdim) : sb1;                    \
    (B1P)[0] = *(const float4*)&b1gn[(jn & 31) * 32 + lg * 4];                   \
    (B1P)[1] = *(const float4*)&b1gn[(jn & 31) * 32 + 16 + lg * 4];              \
    const unsigned short* w2n = cbn + 8192 + ((size_t)((wave * 4) * 64 + lane)) * 8; \
    _Pragma("unroll")                                                            \
    for (int nf = 0; nf < 4; ++nf) (WBP)[nf] = *(const u16x8*)(w2n + nf * 512);  \
    __builtin_amdgcn_sched_barrier(0);                                           \
    /* (2) glds(J+2) */                                                          \
    {                                                                            \
      const int j2 = ((J) + 2 < total) ? (J) + 2 : total - 1;                    \
      const unsigned short* cb2 = CHUNK_PTR(j2);                                 \
      _Pragma("unroll")                                                          \
      for (int qq = 0; qq < 4; ++qq)                                             \
        glds16(cb2 + tid * 8 + qq * 2048, (NXT2) + tid * 8 + qq * 2048);         \
    }                                                                            \
    __builtin_amdgcn_sched_barrier(0);                                           \
    /* (3) wait glds(J): newest 20 = last two iters' vmem */                     \
    asm volatile("s_waitcnt vmcnt(20)" ::: "memory");                            \
    __builtin_amdgcn_sched_barrier(0);                                           \
    /* (4) stage 1 (swapped): D[h][tok] */                                       \
    f32x4 a1[2]; a1[0] = fz; a1[1] = fz;                                         \
    __builtin_amdgcn_s_setprio(1);                                               \
    _Pragma("unroll")                                                            \
    for (int k = 0; k < 8; ++k) {                                                \
      u16x8 w0 = *(const u16x8*)&(CUR)[((k * 2 + 0) * 64 + lane) * 8];           \
      u16x8 w1 = *(const u16x8*)&(CUR)[((k * 2 + 1) * 64 + lane) * 8];           \
      a1[0] = MFMA(w0, xf[k], a1[0]);                                            \
      a1[1] = MFMA(w1, xf[k], a1[1]);                                            \
    }                                                                            \
    __builtin_amdgcn_s_setprio(0);                                               \
    /* (5) gelu (exact sigma identity) + vectorized hid store */                 \
    const float wsc_ = (((J) >> 5) == 0) ? sc0 : ((((J) >> 5) == 1) ? sc1 : sc2);\
    _Pragma("unroll")                                                            \
    for (int hg = 0; hg < 2; ++hg) {                                             \
      ushort4 st;                                                                \
      _Pragma("unroll")                                                          \
      for (int r = 0; r < 4; ++r) {                                              \
        float z = a1[hg][r] + (B1U)[hg][r];                                      \
        float u = z * z;                                                         \
        float tp = z * __builtin_fmaf(u, -0.1029434f, -2.3022117f);              \
        float e = __builtin_amdgcn_exp2f(tp);                                    \
        float rr = __builtin_amdgcn_rcpf(e + 1.0f);                              \
        st[r] = f2bf(z * wsc_ * rr);                                             \
      }                                                                          \
      *(ushort4*)&hid[(wave * 16 + lr) * 44 + hg * 16 + lg * 4] = st;            \
    }                                                                            \
    asm volatile("s_waitcnt lgkmcnt(0)" ::: "memory");                           \
    __builtin_amdgcn_s_barrier();                                                \
    __builtin_amdgcn_sched_barrier(0);                                           \
    /* (6) stage 2: oacc += hid @ W2chunk */                                     \
    u16x8 ha[4];                                                                 \
    _Pragma("unroll")                                                            \
    for (int mf = 0; mf < 4; ++mf)                                               \
      ha[mf] = *(const u16x8*)&hid[(mf * 16 + lr) * 44 + lg * 8];                \
    __builtin_amdgcn_s_setprio(1);                                               \
    _Pragma("unroll")                                                            \
    for (int mf = 0; mf < 4; ++mf)                                               \
      _Pragma("unroll")                                                          \
      for (int nf = 0; nf < 4; ++nf)                                             \
        oacc[mf][nf] = MFMA(ha[mf], (WBU)[nf], oacc[mf][nf]);                    \
    __builtin_amdgcn_s_setprio(0);                                               \
    __builtin_amdgcn_s_barrier();                                                \
    __builtin_amdgcn_sched_barrier(0);                                           \
  }

  for (int j = 0; j < total; j += 2) {
    ITER(j,     c0, c2, b1A, wbA, b1B, wbB);
    ITER(j + 1, c1, c0, b1B, wbB, b1A, wbA);
    unsigned short* tmp = c0; c0 = c2; c2 = c1; c1 = tmp;
  }
#undef ITER
#undef CHUNK_PTR
#undef CHUNK_ID

  // ---- epilogue: bias + store (block owns full 64x256 tile) ----
  float* og = out + ((size_t)b * LSEQ + t * 64) * Ddim;
  #pragma unroll
  for (int nf = 0; nf < 4; ++nf) {
    int dcol = wave * 64 + nf * 16 + lr;
    float bias = sb2[dcol];
    if (wi0 < 4) bias += sc0 * eb2[wi0 * Ddim + dcol];
    if (nm > 1 && wi1 < 4) bias += sc1 * eb2[wi1 * Ddim + dcol];
    if (nm > 2 && wi2 < 4) bias += sc2 * eb2[wi2 * Ddim + dcol];
    #pragma unroll
    for (int mf = 0; mf < 4; ++mf)
      #pragma unroll
      for (int r = 0; r < 4; ++r)
        og[(size_t)(mf * 16 + lg * 4 + r) * Ddim + dcol] = oacc[mf][nf][r] + bias;
  }
}

// ---------------- launch ----------------

extern "C" void kernel_launch(void* const* d_in, const int* in_sizes, int n_in,
                              void* d_out, int out_size, void* d_ws, size_t ws_size,
                              hipStream_t stream) {
  const float* x      = (const float*)d_in[0];
  const float* tc     = (const float*)d_in[1];
  const float* gate_w = (const float*)d_in[2];
  const float* gate_b = (const float*)d_in[3];
  const float* tmod_w = (const float*)d_in[4];
  const float* tmod_b = (const float*)d_in[5];
  const float* ew1    = (const float*)d_in[6];
  const float* eb1    = (const float*)d_in[7];
  const float* ew2    = (const float*)d_in[8];
  const float* eb2    = (const float*)d_in[9];
  const float* sw1    = (const float*)d_in[10];
  const float* sb1    = (const float*)d_in[11];
  const float* sw2    = (const float*)d_in[12];
  const float* sb2    = (const float*)d_in[13];
  float* out = (float*)d_out;

  char* wsb = (char*)d_ws;
  float* ws_part = (float*)wsb;                            // 8*24*256 f32 = 196608 B
  unsigned short* wch = (unsigned short*)(wsb + 196608);   // 5*32*16384 u16 = 10.49 MB

  k1_prep<<<512, 256, 0, stream>>>(x, ws_part, ew1, sw1, ew2, sw2, wch);
  moe_main<<<384, 256, 0, stream>>>(x, wch, eb1, sb1, eb2, sb2, ws_part, tc,
                                    gate_w, gate_b, tmod_w, tmod_b, out);
}